// Round 13
// baseline (693.882 us; speedup 1.0000x reference)
//
#include <hip/hip_runtime.h>
#include <hip/hip_bf16.h>
#include <math.h>

// Problem constants
#define S_LEN   2048
#define D_MOD   512
#define N_HEADS 8
#define D_HEAD  64
#define FF_DIM  2048
#define M_ROWS  16384            // B*S
#define BHSD    8388608          // 8*8*2048*64 elements per Q/K/V tensor

typedef __attribute__((ext_vector_type(8))) __bf16 bf16x8;
typedef __attribute__((ext_vector_type(4))) float  f32x4;
typedef unsigned short u16;

__device__ __forceinline__ u16 f2bf(float f) {           // RNE f32 -> bf16 bits
  unsigned u = __float_as_uint(f);
  u += 0x7fffu + ((u >> 16) & 1u);
  return (u16)(u >> 16);
}
__device__ __forceinline__ float bf2f(u16 h) { return __uint_as_float(((unsigned)h) << 16); }

__device__ __forceinline__ f32x4 mfma16(bf16x8 a, bf16x8 b, f32x4 c) {
  return __builtin_amdgcn_mfma_f32_16x16x32_bf16(a, b, c, 0, 0, 0);
}

// async global->LDS, 16B per lane; lds base wave-uniform (HW adds lane*16)
__device__ __forceinline__ void async16(void* lds, const void* g) {
  __builtin_amdgcn_global_load_lds(
      (const __attribute__((address_space(1))) unsigned int*)g,
      (__attribute__((address_space(3))) unsigned int*)lds, 16, 0, 0);
}

#define BAR()    asm volatile("s_barrier" ::: "memory")
#define WAITV(n) asm volatile("s_waitcnt vmcnt(" #n ")" ::: "memory")
#define WAITL()  asm volatile("s_waitcnt lgkmcnt(0)" ::: "memory")

// XOR swizzle within each 128B group of a 384B row (attn 64x192 bf16 tiles)
__device__ __forceinline__ int swz384(int row, int bir) {
  return row * 384 + ((bir & ~127) | ((bir ^ ((row & 7) << 4)) & 127));
}

// ---------------- fused src->bf16 + gate, one wave per row ----------------
__global__ __launch_bounds__(256) void cvt_gate(const float* __restrict__ src,
                                                const float* __restrict__ Wg,
                                                const float* __restrict__ bg,
                                                u16* __restrict__ xb,
                                                float* __restrict__ gate) {
  const int wid = threadIdx.x >> 6, lane = threadIdx.x & 63;
  const size_t row = (size_t)blockIdx.x * 4 + wid;
  const float4* s = reinterpret_cast<const float4*>(src + row * D_MOD);
  const float4* w = reinterpret_cast<const float4*>(Wg);
  float4 a0 = s[lane * 2], a1 = s[lane * 2 + 1];
  float4 w0 = w[lane * 2], w1 = w[lane * 2 + 1];
  float acc = a0.x * w0.x + a0.y * w0.y + a0.z * w0.z + a0.w * w0.w +
              a1.x * w1.x + a1.y * w1.y + a1.z * w1.z + a1.w * w1.w;
#pragma unroll
  for (int m = 1; m < 64; m <<= 1) acc += __shfl_xor(acc, m);
  ushort4 h0, h1;
  h0.x = f2bf(a0.x); h0.y = f2bf(a0.y); h0.z = f2bf(a0.z); h0.w = f2bf(a0.w);
  h1.x = f2bf(a1.x); h1.y = f2bf(a1.y); h1.z = f2bf(a1.z); h1.w = f2bf(a1.w);
  ushort4* ob = reinterpret_cast<ushort4*>(xb + row * D_MOD);
  ob[lane * 2] = h0; ob[lane * 2 + 1] = h1;
  if (lane == 0) {
    float g = 1.f / (1.f + __expf(-(acc + bg[0])));
    gate[row] = g > 0.f ? g : 0.f;    // THRESH = 0
  }
}

// ---------------- [K,N] f32 -> [N,K] bf16 transpose ----------------
__global__ void transpose_cvt(const float* __restrict__ in, u16* __restrict__ out,
                              int K, int N) {
  __shared__ float t[32][33];
  const int n0 = blockIdx.x * 32, k0 = blockIdx.y * 32;
  const int tx = threadIdx.x, ty = threadIdx.y;   // (32,8)
#pragma unroll
  for (int i = 0; i < 4; ++i)
    t[ty + 8 * i][tx] = in[(size_t)(k0 + ty + 8 * i) * N + n0 + tx];
  __syncthreads();
#pragma unroll
  for (int i = 0; i < 4; ++i)
    out[(size_t)(n0 + ty + 8 * i) * K + k0 + tx] = f2bf(t[tx][ty + 8 * i]);
}

// ------ fused proj split-K reduce + bias + gate + residual(bf16) + layernorm 1 ------
__global__ __launch_bounds__(256) void ln1red_k(const u16* __restrict__ xb,
                                                const float* __restrict__ gate,
                                                const u16* __restrict__ p0,
                                                const u16* __restrict__ p1,
                                                const float* __restrict__ bo,
                                                const float* __restrict__ gam,
                                                const float* __restrict__ bet,
                                                u16* __restrict__ outb) {
  const int wid = threadIdx.x >> 6, lane = threadIdx.x & 63;
  const size_t row = (size_t)blockIdx.x * 4 + wid;
  const size_t base = row * D_MOD;
  const float g = gate[row];
  const ushort4* sp = reinterpret_cast<const ushort4*>(xb + base);
  const ushort4* a  = reinterpret_cast<const ushort4*>(p0 + base);
  const ushort4* c  = reinterpret_cast<const ushort4*>(p1 + base);
  const float4*  bb = reinterpret_cast<const float4*>(bo);
  ushort4 s0 = sp[lane * 2], s1 = sp[lane * 2 + 1];
  ushort4 a0 = a[lane * 2], a1 = a[lane * 2 + 1];
  ushort4 c0 = c[lane * 2], c1 = c[lane * 2 + 1];
  float4 d0 = bb[lane * 2], d1 = bb[lane * 2 + 1];
  float4 v0, v1;
  v0.x = bf2f(s0.x) + g * (bf2f(a0.x) + bf2f(c0.x) + d0.x);
  v0.y = bf2f(s0.y) + g * (bf2f(a0.y) + bf2f(c0.y) + d0.y);
  v0.z = bf2f(s0.z) + g * (bf2f(a0.z) + bf2f(c0.z) + d0.z);
  v0.w = bf2f(s0.w) + g * (bf2f(a0.w) + bf2f(c0.w) + d0.w);
  v1.x = bf2f(s1.x) + g * (bf2f(a1.x) + bf2f(c1.x) + d1.x);
  v1.y = bf2f(s1.y) + g * (bf2f(a1.y) + bf2f(c1.y) + d1.y);
  v1.z = bf2f(s1.z) + g * (bf2f(a1.z) + bf2f(c1.z) + d1.z);
  v1.w = bf2f(s1.w) + g * (bf2f(a1.w) + bf2f(c1.w) + d1.w);
  float s  = v0.x + v0.y + v0.z + v0.w + v1.x + v1.y + v1.z + v1.w;
  float s2 = v0.x * v0.x + v0.y * v0.y + v0.z * v0.z + v0.w * v0.w +
             v1.x * v1.x + v1.y * v1.y + v1.z * v1.z + v1.w * v1.w;
#pragma unroll
  for (int m = 1; m < 64; m <<= 1) { s += __shfl_xor(s, m); s2 += __shfl_xor(s2, m); }
  const float mu = s * (1.0f / 512.0f);
  const float var = s2 * (1.0f / 512.0f) - mu * mu;
  const float rs = 1.0f / sqrtf(var + 1e-5f);
  const float4* gp = reinterpret_cast<const float4*>(gam);
  const float4* bp = reinterpret_cast<const float4*>(bet);
  float4 g0 = gp[lane * 2], g1 = gp[lane * 2 + 1];
  float4 e0 = bp[lane * 2], e1 = bp[lane * 2 + 1];
  ushort4 h0, h1;
  h0.x = f2bf((v0.x - mu) * rs * g0.x + e0.x);  h0.y = f2bf((v0.y - mu) * rs * g0.y + e0.y);
  h0.z = f2bf((v0.z - mu) * rs * g0.z + e0.z);  h0.w = f2bf((v0.w - mu) * rs * g0.w + e0.w);
  h1.x = f2bf((v1.x - mu) * rs * g1.x + e1.x);  h1.y = f2bf((v1.y - mu) * rs * g1.y + e1.y);
  h1.z = f2bf((v1.z - mu) * rs * g1.z + e1.z);  h1.w = f2bf((v1.w - mu) * rs * g1.w + e1.w);
  ushort4* ob = reinterpret_cast<ushort4*>(outb + base);
  ob[lane * 2] = h0; ob[lane * 2 + 1] = h1;
}

// ---------------- fused FF2 split-K reduce + bias + residual + layernorm 2 ----------------
__global__ __launch_bounds__(256) void ln2red_k(const u16* __restrict__ xb,
                                                const u16* __restrict__ p0,
                                                const u16* __restrict__ p1,
                                                const float* __restrict__ b2,
                                                const float* __restrict__ gam,
                                                const float* __restrict__ bet,
                                                float* __restrict__ out) {
  const int wid = threadIdx.x >> 6, lane = threadIdx.x & 63;
  const size_t row = (size_t)blockIdx.x * 4 + wid;
  const size_t base = row * D_MOD;
  const ushort4* xp = reinterpret_cast<const ushort4*>(xb + base);
  const ushort4* q0 = reinterpret_cast<const ushort4*>(p0 + base);
  const ushort4* q1 = reinterpret_cast<const ushort4*>(p1 + base);
  const float4* bb = reinterpret_cast<const float4*>(b2);
  ushort4 h0 = xp[lane * 2], h1 = xp[lane * 2 + 1];
  ushort4 a0 = q0[lane * 2], a1 = q0[lane * 2 + 1];
  ushort4 c0 = q1[lane * 2], c1 = q1[lane * 2 + 1];
  float4 d0 = bb[lane * 2], d1 = bb[lane * 2 + 1];
  float4 v0, v1;
  v0.x = bf2f(h0.x) + bf2f(a0.x) + bf2f(c0.x) + d0.x;
  v0.y = bf2f(h0.y) + bf2f(a0.y) + bf2f(c0.y) + d0.y;
  v0.z = bf2f(h0.z) + bf2f(a0.z) + bf2f(c0.z) + d0.z;
  v0.w = bf2f(h0.w) + bf2f(a0.w) + bf2f(c0.w) + d0.w;
  v1.x = bf2f(h1.x) + bf2f(a1.x) + bf2f(c1.x) + d1.x;
  v1.y = bf2f(h1.y) + bf2f(a1.y) + bf2f(c1.y) + d1.y;
  v1.z = bf2f(h1.z) + bf2f(a1.z) + bf2f(c1.z) + d1.z;
  v1.w = bf2f(h1.w) + bf2f(a1.w) + bf2f(c1.w) + d1.w;
  float s  = v0.x + v0.y + v0.z + v0.w + v1.x + v1.y + v1.z + v1.w;
  float s2 = v0.x * v0.x + v0.y * v0.y + v0.z * v0.z + v0.w * v0.w +
             v1.x * v1.x + v1.y * v1.y + v1.z * v1.z + v1.w * v1.w;
#pragma unroll
  for (int m = 1; m < 64; m <<= 1) { s += __shfl_xor(s, m); s2 += __shfl_xor(s2, m); }
  const float mu = s * (1.0f / 512.0f);
  const float var = s2 * (1.0f / 512.0f) - mu * mu;
  const float rs = 1.0f / sqrtf(var + 1e-5f);
  const float4* gp = reinterpret_cast<const float4*>(gam);
  const float4* bp = reinterpret_cast<const float4*>(bet);
  float4 g0 = gp[lane * 2], g1 = gp[lane * 2 + 1];
  float4 e0 = bp[lane * 2], e1 = bp[lane * 2 + 1];
  float4 o0, o1;
  o0.x = (v0.x - mu) * rs * g0.x + e0.x;  o0.y = (v0.y - mu) * rs * g0.y + e0.y;
  o0.z = (v0.z - mu) * rs * g0.z + e0.z;  o0.w = (v0.w - mu) * rs * g0.w + e0.w;
  o1.x = (v1.x - mu) * rs * g1.x + e1.x;  o1.y = (v1.y - mu) * rs * g1.y + e1.y;
  o1.z = (v1.z - mu) * rs * g1.z + e1.z;  o1.w = (v1.w - mu) * rs * g1.w + e1.w;
  float4* q = reinterpret_cast<float4*>(out + base);
  q[lane * 2] = o0; q[lane * 2 + 1] = o1;
}

// ---------------- 256x256 GEMM: C = A[M,K] @ Bt[N,K]^T ----------------
// DBUF=1: double-buffered 128KB LDS, 4-phase pipelined loop (1 block/CU) — for EPI0.
// DBUF=0: single-buffered 64KB LDS, 2 barriers/K-tile (2 blocks/CU; m114 cross-block overlap).
struct EpiArgs {
  const float* b0; const float* b1; const float* b2;   // biases
  float* outf; u16* outb; u16* outb2;
};

// EPI: 0 = QKV bias + Q/K scatter->bf16[2][B,H,S,dh] (outb) + V -> VT[bh][d][s] (outb2)
//      2 = relu(acc+b1)->bf16 [M,2048]   4 = raw bf16 partial (outb/outb2 by bz), stride 512
template<int EPI, int LD, int NT, int KSLICE, int GX, int GY, int DBUF>
__device__ __forceinline__ void gemm256_body(const u16* __restrict__ A,
                                             const u16* __restrict__ Bt, EpiArgs e) {
  extern __shared__ char smem[];
  char* Asb = smem;            // [DBUF+1 buf][256 rows][128 B], row-swizzled via source
  char* Bsb = smem + (DBUF ? 65536 : 32768);
  const int tid = threadIdx.x;
  const int wid = tid >> 6, lane = tid & 63;
  const int sub = lane >> 4, lc = lane & 15;
  const int wr = wid >> 2, wcn = wid & 3;

  // flatten + bijective XCD swizzle (all grids are multiples of 8 blocks)
  const int nwg = (int)(gridDim.x * gridDim.y * gridDim.z);
  const int orig = ((int)blockIdx.z * (int)gridDim.y + (int)blockIdx.y) * (int)gridDim.x + (int)blockIdx.x;
  const int cpx = nwg >> 3;
  const int wg = (orig & 7) * cpx + (orig >> 3);
  const int bx = wg % GX;
  const int by = (wg / GX) % GY;
  const int bz = wg / (GX * GY);
  const int m0 = by * 256, n0 = bx * 256;
  const int kb = KSLICE * bz;

  const u16* Ab = A + (size_t)m0 * LD;
  const u16* Bb = Bt + (size_t)n0 * LD;

  f32x4 acc[8][4];
#pragma unroll
  for (int i = 0; i < 8; ++i)
#pragma unroll
    for (int j = 0; j < 4; ++j) acc[i][j] = (f32x4){0.f, 0.f, 0.f, 0.f};

  const int lr0 = tid >> 3;   // 0..63
  const int sl  = tid & 7;

  // stage one 256x64 bf16 tile (A or B): 4 x async16 per thread, source pre-swizzled
#define STAGE(BASE, SRC, BUF, KT)                                              \
  {                                                                            \
    const int kk_ = kb + (KT) * 64;                                            \
    _Pragma("unroll")                                                          \
    for (int r_ = 0; r_ < 4; ++r_) {                                           \
      const int lr_ = r_ * 64 + lr0;                                           \
      async16((BASE) + (BUF) * 32768 + r_ * 8192 + wid * 1024,                 \
              (SRC) + (size_t)lr_ * LD + kk_ + ((sl ^ (lr_ & 7)) << 3));       \
    }                                                                          \
  }
#define LDFRAG(BASE, ROW, KS) \
  (*reinterpret_cast<const bf16x8*>((BASE) + (ROW) * 128 + ((((KS) * 64) + sub * 16) ^ (((ROW) & 7) << 4))))

  if constexpr (DBUF) {
    // prologue: B0,A0,B1,A1 (issue order matters for vmcnt counting)
    STAGE(Bsb, Bb, 0, 0);
    STAGE(Asb, Ab, 0, 0);
    STAGE(Bsb, Bb, 1, 1);
    STAGE(Asb, Ab, 1, 1);
    WAITV(8);            // tile 0 landed, tile 1's 8 loads still in flight
    BAR();

    for (int t = 0; t < NT; ++t) {
      const int buf = t & 1;
      char* Abl = Asb + buf * 32768;
      char* Bbl = Bsb + buf * 32768;
      bf16x8 af[4][2], bfr[2][2][2];   // af: qr-half of A; bfr[qc][fc][ks]
      // ---- ph1: read A qr0 (8) + B qc0 (4); MFMA (qr0,qc0) ----
#pragma unroll
      for (int f = 0; f < 4; ++f) {
        const int row = wr * 128 + f * 16 + lc;
#pragma unroll
        for (int ks = 0; ks < 2; ++ks) af[f][ks] = LDFRAG(Abl, row, ks);
      }
#pragma unroll
      for (int f = 0; f < 2; ++f) {
        const int row = wcn * 64 + f * 16 + lc;
#pragma unroll
        for (int ks = 0; ks < 2; ++ks) bfr[0][f][ks] = LDFRAG(Bbl, row, ks);
      }
      __builtin_amdgcn_s_setprio(1);
#pragma unroll
      for (int f = 0; f < 4; ++f)
#pragma unroll
        for (int c = 0; c < 2; ++c)
#pragma unroll
          for (int ks = 0; ks < 2; ++ks)
            acc[f][c] = mfma16(af[f][ks], bfr[0][c][ks], acc[f][c]);
      __builtin_amdgcn_s_setprio(0);
      BAR();
      // ---- ph2: read B qc1 (4); MFMA (qr0,qc1) ----
#pragma unroll
      for (int f = 0; f < 2; ++f) {
        const int row = wcn * 64 + 32 + f * 16 + lc;
#pragma unroll
        for (int ks = 0; ks < 2; ++ks) bfr[1][f][ks] = LDFRAG(Bbl, row, ks);
      }
      __builtin_amdgcn_s_setprio(1);
#pragma unroll
      for (int f = 0; f < 4; ++f)
#pragma unroll
        for (int c = 0; c < 2; ++c)
#pragma unroll
          for (int ks = 0; ks < 2; ++ks)
            acc[f][2 + c] = mfma16(af[f][ks], bfr[1][c][ks], acc[f][2 + c]);
      __builtin_amdgcn_s_setprio(0);
      WAITL();           // all B (and A) LDS reads landed in regs before B region is re-staged
      BAR();
      // ---- ph3: stage B(t+2) into this buf; read A qr1 (8); MFMA (qr1,qc1) ----
      if (t + 2 < NT) STAGE(Bsb, Bb, buf, t + 2);
#pragma unroll
      for (int f = 0; f < 4; ++f) {
        const int row = wr * 128 + 64 + f * 16 + lc;
#pragma unroll
        for (int ks = 0; ks < 2; ++ks) af[f][ks] = LDFRAG(Abl, row, ks);
      }
      __builtin_amdgcn_s_setprio(1);
#pragma unroll
      for (int f = 0; f < 4; ++f)
#pragma unroll
        for (int c = 0; c < 2; ++c)
#pragma unroll
          for (int ks = 0; ks < 2; ++ks)
            acc[4 + f][2 + c] = mfma16(af[f][ks], bfr[1][c][ks], acc[4 + f][2 + c]);
      __builtin_amdgcn_s_setprio(0);
      WAITL();           // A qr1 reads landed before A region is re-staged
      BAR();
      // ---- ph4: stage A(t+2); MFMA (qr1,qc0); counted boundary wait ----
      if (t + 2 < NT) STAGE(Asb, Ab, buf, t + 2);
      __builtin_amdgcn_s_setprio(1);
#pragma unroll
      for (int f = 0; f < 4; ++f)
#pragma unroll
        for (int c = 0; c < 2; ++c)
#pragma unroll
          for (int ks = 0; ks < 2; ++ks)
            acc[4 + f][c] = mfma16(af[f][ks], bfr[0][c][ks], acc[4 + f][c]);
      __builtin_amdgcn_s_setprio(0);
      if (t + 1 < NT) {
        if (t + 2 < NT) { WAITV(8); } else { WAITV(0); }  // leave next-next tile in flight
        BAR();
      }
    }
  } else {
    // single-buffer: stage tile t fully, compute, stage t+1 after the consume barrier.
    STAGE(Bsb, Bb, 0, 0);
    STAGE(Asb, Ab, 0, 0);
    for (int t = 0; t < NT; ++t) {
      WAITV(0);          // this wave's loads landed...
      BAR();             // ...and (via every wave's WAITV) everyone's -> tile t ready
      bf16x8 af[4][2], bfr[2][2][2];
#pragma unroll
      for (int f = 0; f < 2; ++f)
#pragma unroll
        for (int ks = 0; ks < 2; ++ks) {
          bfr[0][f][ks] = LDFRAG(Bsb, wcn * 64 + f * 16 + lc, ks);
          bfr[1][f][ks] = LDFRAG(Bsb, wcn * 64 + 32 + f * 16 + lc, ks);
        }
#pragma unroll
      for (int f = 0; f < 4; ++f)
#pragma unroll
        for (int ks = 0; ks < 2; ++ks) af[f][ks] = LDFRAG(Asb, wr * 128 + f * 16 + lc, ks);
      __builtin_amdgcn_s_setprio(1);
#pragma unroll
      for (int f = 0; f < 4; ++f)
#pragma unroll
        for (int j = 0; j < 4; ++j)
#pragma unroll
          for (int ks = 0; ks < 2; ++ks)
            acc[f][j] = mfma16(af[f][ks], bfr[j >> 1][j & 1][ks], acc[f][j]);
      __builtin_amdgcn_s_setprio(0);
#pragma unroll
      for (int f = 0; f < 4; ++f)
#pragma unroll
        for (int ks = 0; ks < 2; ++ks) af[f][ks] = LDFRAG(Asb, wr * 128 + 64 + f * 16 + lc, ks);
      __builtin_amdgcn_s_setprio(1);
#pragma unroll
      for (int f = 0; f < 4; ++f)
#pragma unroll
        for (int j = 0; j < 4; ++j)
#pragma unroll
          for (int ks = 0; ks < 2; ++ks)
            acc[4 + f][j] = mfma16(af[f][ks], bfr[j >> 1][j & 1][ks], acc[4 + f][j]);
      __builtin_amdgcn_s_setprio(0);
      WAITL();           // all LDS reads landed in regs
      BAR();             // all waves done reading -> safe to overwrite
      if (t + 1 < NT) {
        STAGE(Bsb, Bb, 0, t + 1);
        STAGE(Asb, Ab, 0, t + 1);
      }
    }
  }
#undef STAGE
#undef LDFRAG

  // ---- epilogue ----
  if constexpr (EPI == 2 || EPI == 4) {
    // direct semi-coalesced stores (32B per 16-lane group) — R7-proven best
#pragma unroll
    for (int fr = 0; fr < 8; ++fr) {
      const int row0 = m0 + wr * 128 + fr * 16 + sub * 4;
#pragma unroll
      for (int fc = 0; fc < 4; ++fc) {
        const int col = n0 + wcn * 64 + fc * 16 + lc;
        f32x4 v = acc[fr][fc];
#pragma unroll
        for (int i = 0; i < 4; ++i) {
          const int row = row0 + i;
          const float val = v[i];
          if constexpr (EPI == 2) {
            float o = val + e.b0[col];
            e.outb[(size_t)row * FF_DIM + col] = f2bf(o > 0.f ? o : 0.f);
          } else {
            u16* dst = (bz == 0) ? e.outb : e.outb2;
            dst[(size_t)row * D_MOD + col] = f2bf(val);
          }
        }
      }
    }
  } else {
    // EPI 0: which is block-uniform (n0>>9): 0=Q,1=K -> scatter; 2=V -> LDS transpose + coalesced
    const int which = n0 >> 9;
    const int bbi = m0 >> 11, ss0 = m0 & 2047;
    if (which == 2) {
      __syncthreads();
      u16* Cs = reinterpret_cast<u16*>(smem);   // Cs[nn][s]: 256 x 512B, swizzled
      const int nnb = n0 & 511;
#pragma unroll
      for (int fr = 0; fr < 8; ++fr) {
        const int lrow = wr * 128 + fr * 16 + sub * 4;   // local s
#pragma unroll
        for (int fc = 0; fc < 4; ++fc) {
          const int lcol = wcn * 64 + fc * 16 + lc;       // local nn
          const float bias = e.b2[nnb + lcol];
          f32x4 v = acc[fr][fc];
#pragma unroll
          for (int i = 0; i < 4; ++i) {
            const int row = lrow + i;
            const int sbyte = (row * 2) ^ ((lcol & 7) << 4);
            *reinterpret_cast<u16*>((char*)Cs + lcol * 512 + sbyte) = f2bf(v[i] + bias);
          }
        }
      }
      __syncthreads();
#pragma unroll
      for (int p = 0; p < 16; ++p) {
        const int off = p * 8192 + tid * 16;
        const int nn = off >> 9, cb = off & 511;          // nn = local col, cb = s-bytes
        const int cbs = cb ^ ((nn & 7) << 4);
        uint4 v = *reinterpret_cast<const uint4*>((const char*)Cs + nn * 512 + cbs);
        const int nng = nnb + nn;
        const int hh = nng >> 6, dd = nng & 63;
        *reinterpret_cast<uint4*>(
            (char*)(e.outb2 + (((size_t)bbi * N_HEADS + hh) * D_HEAD + dd) * S_LEN + ss0) + cb) = v;
      }
    } else {
#pragma unroll
      for (int fr = 0; fr < 8; ++fr) {
        const int row0 = m0 + wr * 128 + fr * 16 + sub * 4;
        const int ss = row0 & 2047;
#pragma unroll
        for (int fc = 0; fc < 4; ++fc) {
          const int col = n0 + wcn * 64 + fc * 16 + lc;
          const int nn = col & 511;
          const int hh = nn >> 6, dd = nn & 63;
          const float* bp = (which == 0) ? e.b0 : e.b1;
          const float bias = bp[nn];
          f32x4 v = acc[fr][fc];
#pragma unroll
          for (int i = 0; i < 4; ++i)
            e.outb[(size_t)which * BHSD +
                   (((size_t)bbi * N_HEADS + hh) * S_LEN + ss + i) * D_HEAD + dd]
                = f2bf(v[i] + bias);
        }
      }
    }
  }
}

__global__ __launch_bounds__(512, 2) void k_qkv(const u16* __restrict__ A, const u16* __restrict__ B, EpiArgs e) {
  gemm256_body<0, 512, 8, 0, 6, 64, 1>(A, B, e);
}
__global__ __launch_bounds__(512, 4) void k_ff1(const u16* __restrict__ A, const u16* __restrict__ B, EpiArgs e) {
  gemm256_body<2, 512, 8, 0, 8, 64, 0>(A, B, e);
}
__global__ __launch_bounds__(512, 4) void k_ff2(const u16* __restrict__ A, const u16* __restrict__ B, EpiArgs e) {
  gemm256_body<4, 2048, 16, 1024, 2, 64, 0>(A, B, e);
}
__global__ __launch_bounds__(512, 4) void k_proj(const u16* __restrict__ A, const u16* __restrict__ B, EpiArgs e) {
  gemm256_body<4, 512, 4, 256, 2, 64, 0>(A, B, e);
}

// ---------------- windowed attention: one block per (b,h, 64-query tile) ----------------
// R4-proven compute; V^T band staged via global_load_lds from pre-transposed VTg with
// inverse-swz384 source columns (LDS content identical to R4's VT).
__global__ __launch_bounds__(256)
void attn_k(const u16* __restrict__ Q, const u16* __restrict__ Kt,
            const u16* __restrict__ VTg, u16* __restrict__ Oflat) {
  __shared__ __align__(16) u16 VT[64 * 192];   // V^T (swz384): row=d, col=key
  __shared__ __align__(16) u16 P [64 * 192];   // probs (swz384): row=q, col=key
  __shared__ float tab[256];                   // bias table indexed by dist+127
  const int tid = threadIdx.x;
  const int wid = tid >> 6, lane = tid & 63;
  const int sub = lane >> 4, lc = lane & 15;
  const int qb = blockIdx.x, bh = blockIdx.y;
  const int bb = bh >> 3, hh = bh & 7;
  const int q0 = qb * 64, kstart = q0 - 64;    // 192-key band
  const u16* Qb = Q  + (size_t)bh * S_LEN * D_HEAD;
  const u16* Kb = Kt + (size_t)bh * S_LEN * D_HEAD;
  const u16* Vtb = VTg + (size_t)bh * D_HEAD * S_LEN;   // [d][s]

  // ---- V^T staging: 6 async16/thread, linear LDS dest, inverse-swz source cols ----
#pragma unroll
  for (int it = 0; it < 6; ++it) {
    const int c = (wid * 6 + it) * 64 + lane;  // chunk 0..1535
    const int row = c / 24;                    // d (384B per row = 24 chunks)
    const int bir = (c % 24) * 16;
    const int swz = (bir & ~127) | ((bir ^ ((row & 7) << 4)) & 127);
    int sb = kstart + (swz >> 1);              // 8 s-values per chunk
    sb = sb < 0 ? 0 : (sb > S_LEN - 8 ? S_LEN - 8 : sb);   // clamp; P=0 masks garbage
    async16((char*)VT + (wid * 6 + it) * 1024, Vtb + (size_t)row * S_LEN + sb);
  }

  if (tid < 255) {                             // dist in [-127,127]
    const int di = tid - 127;
    const float fd = (float)di;
    tab[tid] = (di >= -64 && di <= 64)
        ? __expf(-fd * fd * 0.125f) + __cosf(0.06283185307179586f * fd)
        : -1e9f;
  }

  // Q fragments straight from global (A operand: row = lane&15)
  bf16x8 qf[2];
#pragma unroll
  for (int ks = 0; ks < 2; ++ks)
    qf[ks] = *reinterpret_cast<const bf16x8*>(Qb + (size_t)(q0 + wid * 16 + lc) * D_HEAD + ks * 32 + sub * 8);

  // QK^T: 12 col tiles of 16 keys, K fragments straight from global (clamped; masked later)
  f32x4 sc[12];
#pragma unroll
  for (int t = 0; t < 12; ++t) sc[t] = (f32x4){0.f, 0.f, 0.f, 0.f};
#pragma unroll
  for (int ks = 0; ks < 2; ++ks)
#pragma unroll
    for (int t = 0; t < 12; ++t) {
      int kg = kstart + t * 16 + lc;
      int kc = kg < 0 ? 0 : (kg > S_LEN - 1 ? S_LEN - 1 : kg);
      bf16x8 kf = *reinterpret_cast<const bf16x8*>(Kb + (size_t)kc * D_HEAD + ks * 32 + sub * 8);
      sc[t] = mfma16(qf[ks], kf, sc[t]);
    }
  __syncthreads();   // tab + VT ready (barrier drains vmcnt)

  // bias + mask + wave-parallel softmax (row lives across 16 lanes x 12 regs)
  float rmax[4] = {-3e38f, -3e38f, -3e38f, -3e38f};
#pragma unroll
  for (int t = 0; t < 12; ++t) {
    const int kk = t * 16 + lc;
    const int kg = kstart + kk;
    const bool valid = (kg >= 0) && (kg < S_LEN);
#pragma unroll
    for (int r = 0; r < 4; ++r) {
      const int qrow = wid * 16 + sub * 4 + r;
      const float bias = valid ? tab[qrow - kk + 191] : -1e9f;
      const float sv = sc[t][r] * 0.125f + bias;   // 1/sqrt(64)
      sc[t][r] = sv;
      rmax[r] = fmaxf(rmax[r], sv);
    }
  }
#pragma unroll
  for (int m = 1; m < 16; m <<= 1)
#pragma unroll
    for (int r = 0; r < 4; ++r) rmax[r] = fmaxf(rmax[r], __shfl_xor(rmax[r], m));
  float rsum[4] = {0.f, 0.f, 0.f, 0.f};
#pragma unroll
  for (int t = 0; t < 12; ++t)
#pragma unroll
    for (int r = 0; r < 4; ++r) {
      const float p = __expf(sc[t][r] - rmax[r]);
      sc[t][r] = p; rsum[r] += p;
    }
#pragma unroll
  for (int m = 1; m < 16; m <<= 1)
#pragma unroll
    for (int r = 0; r < 4; ++r) rsum[r] += __shfl_xor(rsum[r], m);
  float rinv[4];
#pragma unroll
  for (int r = 0; r < 4; ++r) rinv[r] = 1.0f / rsum[r];
#pragma unroll
  for (int t = 0; t < 12; ++t)
#pragma unroll
    for (int r = 0; r < 4; ++r) {
      const int qrow = wid * 16 + sub * 4 + r;
      *reinterpret_cast<u16*>(reinterpret_cast<char*>(P) + swz384(qrow, (t * 16 + lc) * 2))
          = f2bf(sc[t][r] * rinv[r]);
    }
  __syncthreads();   // P + VT consumable

  // PV: out[64q][64d], K-dim = 192 keys
  f32x4 oacc[4];
#pragma unroll
  for (int t = 0; t < 4; ++t) oacc[t] = (f32x4){0.f, 0.f, 0.f, 0.f};
  const int arow = wid * 16 + lc;
#pragma unroll
  for (int ks = 0; ks < 6; ++ks) {
    const int bir = ks * 64 + sub * 16;
    bf16x8 pa = *reinterpret_cast<const bf16x8*>(reinterpret_cast<char*>(P) + swz384(arow, bir));
#pragma unroll
    for (int t = 0; t < 4; ++t) {
      bf16x8 vb = *reinterpret_cast<const bf16x8*>(reinterpret_cast<char*>(VT) + swz384(t * 16 + lc, bir));
      oacc[t] = mfma16(pa, vb, oacc[t]);
    }
  }

  // write to [B,S,H*dh] bf16
  const size_t obase = ((size_t)bb * S_LEN + q0) * D_MOD + hh * D_HEAD;
#pragma unroll
  for (int t = 0; t < 4; ++t)
#pragma unroll
    for (int r = 0; r < 4; ++r) {
      const int qrow = wid * 16 + sub * 4 + r;
      Oflat[obase + (size_t)qrow * D_MOD + t * 16 + lc] = f2bf(oacc[t][r]);
    }
}

// ---------------- launch ----------------
extern "C" void kernel_launch(void* const* d_in, const int* in_sizes, int n_in,
                              void* d_out, int out_size, void* d_ws, size_t ws_size,
                              hipStream_t stream) {
  (void)in_sizes; (void)n_in; (void)out_size; (void)ws_size;
  const float* src  = (const float*)d_in[0];
  const float* Wq   = (const float*)d_in[1];
  const float* bq   = (const float*)d_in[2];
  const float* Wk   = (const float*)d_in[3];
  const float* bk   = (const float*)d_in[4];
  const float* Wv   = (const float*)d_in[5];
  const float* bv   = (const float*)d_in[6];
  const float* Wo   = (const float*)d_in[7];
  const float* bo   = (const float*)d_in[8];
  const float* Wg   = (const float*)d_in[9];
  const float* bg   = (const float*)d_in[10];
  const float* W1   = (const float*)d_in[11];
  const float* b1   = (const float*)d_in[12];
  const float* W2   = (const float*)d_in[13];
  const float* b2   = (const float*)d_in[14];
  const float* ln1g = (const float*)d_in[15];
  const float* ln1b = (const float*)d_in[16];
  const float* ln2g = (const float*)d_in[17];
  const float* ln2b = (const float*)d_in[18];
  float* out = (float*)d_out;

  char* ws = (char*)d_ws;
  u16*   WqkvT  = (u16*)  (ws + 0);            //  1,572,864
  u16*   WoT    = (u16*)  (ws + 1572864);      //    524,288
  u16*   W1T    = (u16*)  (ws + 2097152);      //  2,097,152
  u16*   W2T    = (u16*)  (ws + 4194304);      //  2,097,152
  float* gatef  = (float*)(ws + 6291456);      //     65,536
  u16*   Xbf    = (u16*)  (ws + 6356992);      // 16,777,216  [live until FF1 overwrites]
  u16*   QKVbf  = (u16*)  (ws + 23134208);     // 50,331,648  (Q,K planes; V plane unused)
  u16*   attnfl = (u16*)  (ws + 73465856);     // 16,777,216  [dead after proj]
  u16*   pr0    = (u16*)  (ws + 90243072);     // 16,777,216  (proj/ff2 partial z=0)
  u16*   pr1    = (u16*)  (ws + 107020288);    // 16,777,216  (proj/ff2 partial z=1)
  u16*   xbf2   = (u16*)  (ws + 123797504);    // 16,777,216  [live to end]
  u16*   VTg    = (u16*)  (ws + 140574720);    // 16,777,216  (V^T [bh][d][s]) -> 157,351,936 total
  u16*   hbuf   = Xbf;                         // FF1 out: 67,108,864 = Xbf+QKVbf regions
  u16*   pf0    = pr0;                         // FF2 partials reuse proj partials
  u16*   pf1    = pr1;

  // set once per call (idempotent; errors ignored — first, uncaptured, call sticks)
  (void)hipFuncSetAttribute((const void*)k_qkv,  hipFuncAttributeMaxDynamicSharedMemorySize, 131072);
  (void)hipFuncSetAttribute((const void*)k_ff1,  hipFuncAttributeMaxDynamicSharedMemorySize, 65536);
  (void)hipFuncSetAttribute((const void*)k_ff2,  hipFuncAttributeMaxDynamicSharedMemorySize, 65536);
  (void)hipFuncSetAttribute((const void*)k_proj, hipFuncAttributeMaxDynamicSharedMemorySize, 65536);

  dim3 tb(32, 8);
  cvt_gate<<<4096, 256, 0, stream>>>(src, Wg, bg, Xbf, gatef);
  transpose_cvt<<<dim3(16, 16), tb, 0, stream>>>(Wq, WqkvT,             512, 512);
  transpose_cvt<<<dim3(16, 16), tb, 0, stream>>>(Wk, WqkvT + 512 * 512, 512, 512);
  transpose_cvt<<<dim3(16, 16), tb, 0, stream>>>(Wv, WqkvT + 2 * 512 * 512, 512, 512);
  transpose_cvt<<<dim3(16, 16), tb, 0, stream>>>(Wo, WoT, 512, 512);
  transpose_cvt<<<dim3(64, 16), tb, 0, stream>>>(W1, W1T, 512, 2048);
  transpose_cvt<<<dim3(16, 64), tb, 0, stream>>>(W2, W2T, 2048, 512);

  EpiArgs e1{bq, bk, bv, nullptr, QKVbf, VTg};
  k_qkv<<<dim3(6, 64, 1), 512, 131072, stream>>>(Xbf, WqkvT, e1);

  attn_k<<<dim3(32, 64), 256, 0, stream>>>(QKVbf, QKVbf + BHSD, VTg, attnfl);

  EpiArgs e2{nullptr, nullptr, nullptr, nullptr, pr0, pr1};
  k_proj<<<dim3(2, 64, 2), 512, 65536, stream>>>(attnfl, WoT, e2);

  ln1red_k<<<4096, 256, 0, stream>>>(Xbf, gatef, pr0, pr1, bo, ln1g, ln1b, xbf2);

  EpiArgs e3{b1, nullptr, nullptr, nullptr, hbuf, nullptr};
  k_ff1<<<dim3(8, 64, 1), 512, 65536, stream>>>(xbf2, W1T, e3);

  EpiArgs e4{nullptr, nullptr, nullptr, nullptr, pf0, pf1};
  k_ff2<<<dim3(2, 64, 2), 512, 65536, stream>>>(hbuf, W2T, e4);

  ln2red_k<<<4096, 256, 0, stream>>>(xbf2, pf0, pf1, b2, ln2g, ln2b, out);
}

// Round 14
// 215.881 us; speedup vs baseline: 3.2142x; 3.2142x over previous
//
#include <hip/hip_runtime.h>
#include <hip/hip_bf16.h>
#include <math.h>

// Problem constants
#define S_LEN   2048
#define D_MOD   512
#define N_HEADS 8
#define D_HEAD  64
#define FF_DIM  2048
#define M_ROWS  16384            // B*S
#define BHSD    8388608          // 8*8*2048*64 elements per Q/K/V tensor

typedef __attribute__((ext_vector_type(8))) __bf16 bf16x8;
typedef __attribute__((ext_vector_type(4))) float  f32x4;
typedef unsigned short u16;

__device__ __forceinline__ u16 f2bf(float f) {           // RNE f32 -> bf16 bits
  unsigned u = __float_as_uint(f);
  u += 0x7fffu + ((u >> 16) & 1u);
  return (u16)(u >> 16);
}
__device__ __forceinline__ float bf2f(u16 h) { return __uint_as_float(((unsigned)h) << 16); }

__device__ __forceinline__ f32x4 mfma16(bf16x8 a, bf16x8 b, f32x4 c) {
  return __builtin_amdgcn_mfma_f32_16x16x32_bf16(a, b, c, 0, 0, 0);
}

// async global->LDS, 16B per lane; lds base wave-uniform (HW adds lane*16)
__device__ __forceinline__ void async16(void* lds, const void* g) {
  __builtin_amdgcn_global_load_lds(
      (const __attribute__((address_space(1))) unsigned int*)g,
      (__attribute__((address_space(3))) unsigned int*)lds, 16, 0, 0);
}

#define BAR()    asm volatile("s_barrier" ::: "memory")
#define WAITV(n) asm volatile("s_waitcnt vmcnt(" #n ")" ::: "memory")
#define WAITL()  asm volatile("s_waitcnt lgkmcnt(0)" ::: "memory")

// XOR swizzle within each 128B group of a 384B row (attn 64x192 bf16 tiles)
__device__ __forceinline__ int swz384(int row, int bir) {
  return row * 384 + ((bir & ~127) | ((bir ^ ((row & 7) << 4)) & 127));
}

// ---------------- fused src->bf16 + gate, one wave per row ----------------
__global__ __launch_bounds__(256) void cvt_gate(const float* __restrict__ src,
                                                const float* __restrict__ Wg,
                                                const float* __restrict__ bg,
                                                u16* __restrict__ xb,
                                                float* __restrict__ gate) {
  const int wid = threadIdx.x >> 6, lane = threadIdx.x & 63;
  const size_t row = (size_t)blockIdx.x * 4 + wid;
  const float4* s = reinterpret_cast<const float4*>(src + row * D_MOD);
  const float4* w = reinterpret_cast<const float4*>(Wg);
  float4 a0 = s[lane * 2], a1 = s[lane * 2 + 1];
  float4 w0 = w[lane * 2], w1 = w[lane * 2 + 1];
  float acc = a0.x * w0.x + a0.y * w0.y + a0.z * w0.z + a0.w * w0.w +
              a1.x * w1.x + a1.y * w1.y + a1.z * w1.z + a1.w * w1.w;
#pragma unroll
  for (int m = 1; m < 64; m <<= 1) acc += __shfl_xor(acc, m);
  ushort4 h0, h1;
  h0.x = f2bf(a0.x); h0.y = f2bf(a0.y); h0.z = f2bf(a0.z); h0.w = f2bf(a0.w);
  h1.x = f2bf(a1.x); h1.y = f2bf(a1.y); h1.z = f2bf(a1.z); h1.w = f2bf(a1.w);
  ushort4* ob = reinterpret_cast<ushort4*>(xb + row * D_MOD);
  ob[lane * 2] = h0; ob[lane * 2 + 1] = h1;
  if (lane == 0) {
    float g = 1.f / (1.f + __expf(-(acc + bg[0])));
    gate[row] = g > 0.f ? g : 0.f;    // THRESH = 0
  }
}

// ---------------- [K,N] f32 -> [N,K] bf16 transpose ----------------
__global__ void transpose_cvt(const float* __restrict__ in, u16* __restrict__ out,
                              int K, int N) {
  __shared__ float t[32][33];
  const int n0 = blockIdx.x * 32, k0 = blockIdx.y * 32;
  const int tx = threadIdx.x, ty = threadIdx.y;   // (32,8)
#pragma unroll
  for (int i = 0; i < 4; ++i)
    t[ty + 8 * i][tx] = in[(size_t)(k0 + ty + 8 * i) * N + n0 + tx];
  __syncthreads();
#pragma unroll
  for (int i = 0; i < 4; ++i)
    out[(size_t)(n0 + ty + 8 * i) * K + k0 + tx] = f2bf(t[tx][ty + 8 * i]);
}

// ------ fused proj split-K reduce + bias + gate + residual(bf16) + layernorm 1 ------
__global__ __launch_bounds__(256) void ln1red_k(const u16* __restrict__ xb,
                                                const float* __restrict__ gate,
                                                const u16* __restrict__ p0,
                                                const u16* __restrict__ p1,
                                                const float* __restrict__ bo,
                                                const float* __restrict__ gam,
                                                const float* __restrict__ bet,
                                                u16* __restrict__ outb) {
  const int wid = threadIdx.x >> 6, lane = threadIdx.x & 63;
  const size_t row = (size_t)blockIdx.x * 4 + wid;
  const size_t base = row * D_MOD;
  const float g = gate[row];
  const ushort4* sp = reinterpret_cast<const ushort4*>(xb + base);
  const ushort4* a  = reinterpret_cast<const ushort4*>(p0 + base);
  const ushort4* c  = reinterpret_cast<const ushort4*>(p1 + base);
  const float4*  bb = reinterpret_cast<const float4*>(bo);
  ushort4 s0 = sp[lane * 2], s1 = sp[lane * 2 + 1];
  ushort4 a0 = a[lane * 2], a1 = a[lane * 2 + 1];
  ushort4 c0 = c[lane * 2], c1 = c[lane * 2 + 1];
  float4 d0 = bb[lane * 2], d1 = bb[lane * 2 + 1];
  float4 v0, v1;
  v0.x = bf2f(s0.x) + g * (bf2f(a0.x) + bf2f(c0.x) + d0.x);
  v0.y = bf2f(s0.y) + g * (bf2f(a0.y) + bf2f(c0.y) + d0.y);
  v0.z = bf2f(s0.z) + g * (bf2f(a0.z) + bf2f(c0.z) + d0.z);
  v0.w = bf2f(s0.w) + g * (bf2f(a0.w) + bf2f(c0.w) + d0.w);
  v1.x = bf2f(s1.x) + g * (bf2f(a1.x) + bf2f(c1.x) + d1.x);
  v1.y = bf2f(s1.y) + g * (bf2f(a1.y) + bf2f(c1.y) + d1.y);
  v1.z = bf2f(s1.z) + g * (bf2f(a1.z) + bf2f(c1.z) + d1.z);
  v1.w = bf2f(s1.w) + g * (bf2f(a1.w) + bf2f(c1.w) + d1.w);
  float s  = v0.x + v0.y + v0.z + v0.w + v1.x + v1.y + v1.z + v1.w;
  float s2 = v0.x * v0.x + v0.y * v0.y + v0.z * v0.z + v0.w * v0.w +
             v1.x * v1.x + v1.y * v1.y + v1.z * v1.z + v1.w * v1.w;
#pragma unroll
  for (int m = 1; m < 64; m <<= 1) { s += __shfl_xor(s, m); s2 += __shfl_xor(s2, m); }
  const float mu = s * (1.0f / 512.0f);
  const float var = s2 * (1.0f / 512.0f) - mu * mu;
  const float rs = 1.0f / sqrtf(var + 1e-5f);
  const float4* gp = reinterpret_cast<const float4*>(gam);
  const float4* bp = reinterpret_cast<const float4*>(bet);
  float4 g0 = gp[lane * 2], g1 = gp[lane * 2 + 1];
  float4 e0 = bp[lane * 2], e1 = bp[lane * 2 + 1];
  ushort4 h0, h1;
  h0.x = f2bf((v0.x - mu) * rs * g0.x + e0.x);  h0.y = f2bf((v0.y - mu) * rs * g0.y + e0.y);
  h0.z = f2bf((v0.z - mu) * rs * g0.z + e0.z);  h0.w = f2bf((v0.w - mu) * rs * g0.w + e0.w);
  h1.x = f2bf((v1.x - mu) * rs * g1.x + e1.x);  h1.y = f2bf((v1.y - mu) * rs * g1.y + e1.y);
  h1.z = f2bf((v1.z - mu) * rs * g1.z + e1.z);  h1.w = f2bf((v1.w - mu) * rs * g1.w + e1.w);
  ushort4* ob = reinterpret_cast<ushort4*>(outb + base);
  ob[lane * 2] = h0; ob[lane * 2 + 1] = h1;
}

// ---------------- fused FF2 split-K reduce + bias + residual + layernorm 2 ----------------
__global__ __launch_bounds__(256) void ln2red_k(const u16* __restrict__ xb,
                                                const u16* __restrict__ p0,
                                                const u16* __restrict__ p1,
                                                const float* __restrict__ b2,
                                                const float* __restrict__ gam,
                                                const float* __restrict__ bet,
                                                float* __restrict__ out) {
  const int wid = threadIdx.x >> 6, lane = threadIdx.x & 63;
  const size_t row = (size_t)blockIdx.x * 4 + wid;
  const size_t base = row * D_MOD;
  const ushort4* xp = reinterpret_cast<const ushort4*>(xb + base);
  const ushort4* q0 = reinterpret_cast<const ushort4*>(p0 + base);
  const ushort4* q1 = reinterpret_cast<const ushort4*>(p1 + base);
  const float4* bb = reinterpret_cast<const float4*>(b2);
  ushort4 h0 = xp[lane * 2], h1 = xp[lane * 2 + 1];
  ushort4 a0 = q0[lane * 2], a1 = q0[lane * 2 + 1];
  ushort4 c0 = q1[lane * 2], c1 = q1[lane * 2 + 1];
  float4 d0 = bb[lane * 2], d1 = bb[lane * 2 + 1];
  float4 v0, v1;
  v0.x = bf2f(h0.x) + bf2f(a0.x) + bf2f(c0.x) + d0.x;
  v0.y = bf2f(h0.y) + bf2f(a0.y) + bf2f(c0.y) + d0.y;
  v0.z = bf2f(h0.z) + bf2f(a0.z) + bf2f(c0.z) + d0.z;
  v0.w = bf2f(h0.w) + bf2f(a0.w) + bf2f(c0.w) + d0.w;
  v1.x = bf2f(h1.x) + bf2f(a1.x) + bf2f(c1.x) + d1.x;
  v1.y = bf2f(h1.y) + bf2f(a1.y) + bf2f(c1.y) + d1.y;
  v1.z = bf2f(h1.z) + bf2f(a1.z) + bf2f(c1.z) + d1.z;
  v1.w = bf2f(h1.w) + bf2f(a1.w) + bf2f(c1.w) + d1.w;
  float s  = v0.x + v0.y + v0.z + v0.w + v1.x + v1.y + v1.z + v1.w;
  float s2 = v0.x * v0.x + v0.y * v0.y + v0.z * v0.z + v0.w * v0.w +
             v1.x * v1.x + v1.y * v1.y + v1.z * v1.z + v1.w * v1.w;
#pragma unroll
  for (int m = 1; m < 64; m <<= 1) { s += __shfl_xor(s, m); s2 += __shfl_xor(s2, m); }
  const float mu = s * (1.0f / 512.0f);
  const float var = s2 * (1.0f / 512.0f) - mu * mu;
  const float rs = 1.0f / sqrtf(var + 1e-5f);
  const float4* gp = reinterpret_cast<const float4*>(gam);
  const float4* bp = reinterpret_cast<const float4*>(bet);
  float4 g0 = gp[lane * 2], g1 = gp[lane * 2 + 1];
  float4 e0 = bp[lane * 2], e1 = bp[lane * 2 + 1];
  float4 o0, o1;
  o0.x = (v0.x - mu) * rs * g0.x + e0.x;  o0.y = (v0.y - mu) * rs * g0.y + e0.y;
  o0.z = (v0.z - mu) * rs * g0.z + e0.z;  o0.w = (v0.w - mu) * rs * g0.w + e0.w;
  o1.x = (v1.x - mu) * rs * g1.x + e1.x;  o1.y = (v1.y - mu) * rs * g1.y + e1.y;
  o1.z = (v1.z - mu) * rs * g1.z + e1.z;  o1.w = (v1.w - mu) * rs * g1.w + e1.w;
  float4* q = reinterpret_cast<float4*>(out + base);
  q[lane * 2] = o0; q[lane * 2 + 1] = o1;
}

// ---------------- 256x256 deep-pipelined GEMM: C = A[M,K] @ Bt[N,K]^T ----------------
struct EpiArgs {
  const float* b0; const float* b1; const float* b2;   // biases
  float* outf; u16* outb; u16* outb2;
};

// EPI: 0 = QKV bias + Q/K scatter->bf16[2][B,H,S,dh] (outb) + V -> VT[bh][d][s] (outb2)
//      2 = relu(acc+b1)->bf16 [M,2048]   4 = raw bf16 partial (outb/outb2 by bz), stride 512
template<int EPI, int LD, int NT, int KSLICE, int GX, int GY>
__device__ __forceinline__ void gemm256_body(const u16* __restrict__ A,
                                             const u16* __restrict__ Bt, EpiArgs e) {
  extern __shared__ char smem[];
  char* Asb = smem;            // [2 buf][256 rows][128 B], row-swizzled via source
  char* Bsb = smem + 65536;
  const int tid = threadIdx.x;
  const int wid = tid >> 6, lane = tid & 63;
  const int sub = lane >> 4, lc = lane & 15;
  const int wr = wid >> 2, wcn = wid & 3;

  // flatten + bijective XCD swizzle (all grids are multiples of 8 blocks)
  const int nwg = (int)(gridDim.x * gridDim.y * gridDim.z);
  const int orig = ((int)blockIdx.z * (int)gridDim.y + (int)blockIdx.y) * (int)gridDim.x + (int)blockIdx.x;
  const int cpx = nwg >> 3;
  const int wg = (orig & 7) * cpx + (orig >> 3);
  const int bx = wg % GX;
  const int by = (wg / GX) % GY;
  const int bz = wg / (GX * GY);
  const int m0 = by * 256, n0 = bx * 256;
  const int kb = KSLICE * bz;

  const u16* Ab = A + (size_t)m0 * LD;
  const u16* Bb = Bt + (size_t)n0 * LD;

  f32x4 acc[8][4];
#pragma unroll
  for (int i = 0; i < 8; ++i)
#pragma unroll
    for (int j = 0; j < 4; ++j) acc[i][j] = (f32x4){0.f, 0.f, 0.f, 0.f};

  const int lr0 = tid >> 3;   // 0..63
  const int sl  = tid & 7;

  // stage one 256x64 bf16 tile (A or B): 4 x async16 per thread, source pre-swizzled
#define STAGE(BASE, SRC, BUF, KT)                                              \
  {                                                                            \
    const int kk_ = kb + (KT) * 64;                                            \
    _Pragma("unroll")                                                          \
    for (int r_ = 0; r_ < 4; ++r_) {                                           \
      const int lr_ = r_ * 64 + lr0;                                           \
      async16((BASE) + (BUF) * 32768 + r_ * 8192 + wid * 1024,                 \
              (SRC) + (size_t)lr_ * LD + kk_ + ((sl ^ (lr_ & 7)) << 3));       \
    }                                                                          \
  }
#define LDFRAG(BASE, ROW, KS) \
  (*reinterpret_cast<const bf16x8*>((BASE) + (ROW) * 128 + ((((KS) * 64) + sub * 16) ^ (((ROW) & 7) << 4))))

  // prologue: B0,A0,B1,A1 (issue order matters for vmcnt counting)
  STAGE(Bsb, Bb, 0, 0);
  STAGE(Asb, Ab, 0, 0);
  STAGE(Bsb, Bb, 1, 1);
  STAGE(Asb, Ab, 1, 1);
  WAITV(8);            // tile 0 landed, tile 1's 8 loads still in flight
  BAR();

  for (int t = 0; t < NT; ++t) {
    const int buf = t & 1;
    char* Abl = Asb + buf * 32768;
    char* Bbl = Bsb + buf * 32768;
    bf16x8 af[4][2], bfr[2][2][2];   // af: qr-half of A; bfr[qc][fc][ks]
    // ---- ph1: read A qr0 (8) + B qc0 (4); MFMA (qr0,qc0) ----
#pragma unroll
    for (int f = 0; f < 4; ++f) {
      const int row = wr * 128 + f * 16 + lc;
#pragma unroll
      for (int ks = 0; ks < 2; ++ks) af[f][ks] = LDFRAG(Abl, row, ks);
    }
#pragma unroll
    for (int f = 0; f < 2; ++f) {
      const int row = wcn * 64 + f * 16 + lc;
#pragma unroll
      for (int ks = 0; ks < 2; ++ks) bfr[0][f][ks] = LDFRAG(Bbl, row, ks);
    }
    __builtin_amdgcn_s_setprio(1);
#pragma unroll
    for (int f = 0; f < 4; ++f)
#pragma unroll
      for (int c = 0; c < 2; ++c)
#pragma unroll
        for (int ks = 0; ks < 2; ++ks)
          acc[f][c] = mfma16(af[f][ks], bfr[0][c][ks], acc[f][c]);
    __builtin_amdgcn_s_setprio(0);
    BAR();
    // ---- ph2: read B qc1 (4); MFMA (qr0,qc1) ----
#pragma unroll
    for (int f = 0; f < 2; ++f) {
      const int row = wcn * 64 + 32 + f * 16 + lc;
#pragma unroll
      for (int ks = 0; ks < 2; ++ks) bfr[1][f][ks] = LDFRAG(Bbl, row, ks);
    }
    __builtin_amdgcn_s_setprio(1);
#pragma unroll
    for (int f = 0; f < 4; ++f)
#pragma unroll
      for (int c = 0; c < 2; ++c)
#pragma unroll
        for (int ks = 0; ks < 2; ++ks)
          acc[f][2 + c] = mfma16(af[f][ks], bfr[1][c][ks], acc[f][2 + c]);
    __builtin_amdgcn_s_setprio(0);
    WAITL();           // all B (and A) LDS reads landed in regs before B region is re-staged
    BAR();
    // ---- ph3: stage B(t+2) into this buf; read A qr1 (8); MFMA (qr1,qc1) ----
    if (t + 2 < NT) STAGE(Bsb, Bb, buf, t + 2);
#pragma unroll
    for (int f = 0; f < 4; ++f) {
      const int row = wr * 128 + 64 + f * 16 + lc;
#pragma unroll
      for (int ks = 0; ks < 2; ++ks) af[f][ks] = LDFRAG(Abl, row, ks);
    }
    __builtin_amdgcn_s_setprio(1);
#pragma unroll
    for (int f = 0; f < 4; ++f)
#pragma unroll
      for (int c = 0; c < 2; ++c)
#pragma unroll
        for (int ks = 0; ks < 2; ++ks)
          acc[4 + f][2 + c] = mfma16(af[f][ks], bfr[1][c][ks], acc[4 + f][2 + c]);
    __builtin_amdgcn_s_setprio(0);
    WAITL();           // A qr1 reads landed before A region is re-staged
    BAR();
    // ---- ph4: stage A(t+2); MFMA (qr1,qc0); counted boundary wait ----
    if (t + 2 < NT) STAGE(Asb, Ab, buf, t + 2);
    __builtin_amdgcn_s_setprio(1);
#pragma unroll
    for (int f = 0; f < 4; ++f)
#pragma unroll
      for (int c = 0; c < 2; ++c)
#pragma unroll
        for (int ks = 0; ks < 2; ++ks)
          acc[4 + f][c] = mfma16(af[f][ks], bfr[0][c][ks], acc[4 + f][c]);
    __builtin_amdgcn_s_setprio(0);
    if (t + 1 < NT) {
      if (t + 2 < NT) { WAITV(8); } else { WAITV(0); }  // leave next-next tile in flight
      BAR();
    }
  }
#undef STAGE
#undef LDFRAG

  // ---- epilogue ----
  if constexpr (EPI == 2 || EPI == 4) {
    // direct semi-coalesced stores (32B per 16-lane group) — R7-proven best
#pragma unroll
    for (int fr = 0; fr < 8; ++fr) {
      const int row0 = m0 + wr * 128 + fr * 16 + sub * 4;
#pragma unroll
      for (int fc = 0; fc < 4; ++fc) {
        const int col = n0 + wcn * 64 + fc * 16 + lc;
        f32x4 v = acc[fr][fc];
#pragma unroll
        for (int i = 0; i < 4; ++i) {
          const int row = row0 + i;
          const float val = v[i];
          if constexpr (EPI == 2) {
            float o = val + e.b0[col];
            e.outb[(size_t)row * FF_DIM + col] = f2bf(o > 0.f ? o : 0.f);
          } else {
            u16* dst = (bz == 0) ? e.outb : e.outb2;
            dst[(size_t)row * D_MOD + col] = f2bf(val);
          }
        }
      }
    }
  } else {
    // EPI 0: which is block-uniform (n0>>9): 0=Q,1=K -> scatter; 2=V -> LDS transpose + coalesced
    const int which = n0 >> 9;
    const int bbi = m0 >> 11, ss0 = m0 & 2047;
    if (which == 2) {
      __syncthreads();
      u16* Cs = reinterpret_cast<u16*>(smem);   // Cs[nn][s]: 256 x 512B, swizzled
      const int nnb = n0 & 511;
#pragma unroll
      for (int fr = 0; fr < 8; ++fr) {
        const int lrow = wr * 128 + fr * 16 + sub * 4;   // local s
#pragma unroll
        for (int fc = 0; fc < 4; ++fc) {
          const int lcol = wcn * 64 + fc * 16 + lc;       // local nn
          const float bias = e.b2[nnb + lcol];
          f32x4 v = acc[fr][fc];
#pragma unroll
          for (int i = 0; i < 4; ++i) {
            const int row = lrow + i;
            const int sbyte = (row * 2) ^ ((lcol & 7) << 4);
            *reinterpret_cast<u16*>((char*)Cs + lcol * 512 + sbyte) = f2bf(v[i] + bias);
          }
        }
      }
      __syncthreads();
#pragma unroll
      for (int p = 0; p < 16; ++p) {
        const int off = p * 8192 + tid * 16;
        const int nn = off >> 9, cb = off & 511;          // nn = local col, cb = s-bytes
        const int cbs = cb ^ ((nn & 7) << 4);
        uint4 v = *reinterpret_cast<const uint4*>((const char*)Cs + nn * 512 + cbs);
        const int nng = nnb + nn;
        const int hh = nng >> 6, dd = nng & 63;
        *reinterpret_cast<uint4*>(
            (char*)(e.outb2 + (((size_t)bbi * N_HEADS + hh) * D_HEAD + dd) * S_LEN + ss0) + cb) = v;
      }
    } else {
#pragma unroll
      for (int fr = 0; fr < 8; ++fr) {
        const int row0 = m0 + wr * 128 + fr * 16 + sub * 4;
        const int ss = row0 & 2047;
#pragma unroll
        for (int fc = 0; fc < 4; ++fc) {
          const int col = n0 + wcn * 64 + fc * 16 + lc;
          const int nn = col & 511;
          const int hh = nn >> 6, dd = nn & 63;
          const float* bp = (which == 0) ? e.b0 : e.b1;
          const float bias = bp[nn];
          f32x4 v = acc[fr][fc];
#pragma unroll
          for (int i = 0; i < 4; ++i)
            e.outb[(size_t)which * BHSD +
                   (((size_t)bbi * N_HEADS + hh) * S_LEN + ss + i) * D_HEAD + dd]
                = f2bf(v[i] + bias);
        }
      }
    }
  }
}

__global__ __launch_bounds__(512, 2) void k_qkv(const u16* __restrict__ A, const u16* __restrict__ B, EpiArgs e) {
  gemm256_body<0, 512, 8, 0, 6, 64>(A, B, e);
}
__global__ __launch_bounds__(512, 2) void k_ff1(const u16* __restrict__ A, const u16* __restrict__ B, EpiArgs e) {
  gemm256_body<2, 512, 8, 0, 8, 64>(A, B, e);
}
__global__ __launch_bounds__(512, 2) void k_ff2(const u16* __restrict__ A, const u16* __restrict__ B, EpiArgs e) {
  gemm256_body<4, 2048, 16, 1024, 2, 64>(A, B, e);
}
__global__ __launch_bounds__(512, 2) void k_proj(const u16* __restrict__ A, const u16* __restrict__ B, EpiArgs e) {
  gemm256_body<4, 512, 4, 256, 2, 64>(A, B, e);
}

// ---------------- windowed attention: one block per (b,h, 64-query tile) ----------------
// R4-proven compute; V^T band staged via global_load_lds from pre-transposed VTg with
// inverse-swz384 source columns (LDS content identical to R4's VT).
__global__ __launch_bounds__(256)
void attn_k(const u16* __restrict__ Q, const u16* __restrict__ Kt,
            const u16* __restrict__ VTg, u16* __restrict__ Oflat) {
  __shared__ __align__(16) u16 VT[64 * 192];   // V^T (swz384): row=d, col=key
  __shared__ __align__(16) u16 P [64 * 192];   // probs (swz384): row=q, col=key
  __shared__ float tab[256];                   // bias table indexed by dist+127
  const int tid = threadIdx.x;
  const int wid = tid >> 6, lane = tid & 63;
  const int sub = lane >> 4, lc = lane & 15;
  const int qb = blockIdx.x, bh = blockIdx.y;
  const int bb = bh >> 3, hh = bh & 7;
  const int q0 = qb * 64, kstart = q0 - 64;    // 192-key band
  const u16* Qb = Q  + (size_t)bh * S_LEN * D_HEAD;
  const u16* Kb = Kt + (size_t)bh * S_LEN * D_HEAD;
  const u16* Vtb = VTg + (size_t)bh * D_HEAD * S_LEN;   // [d][s]

  // ---- V^T staging: 6 async16/thread, linear LDS dest, inverse-swz source cols ----
#pragma unroll
  for (int it = 0; it < 6; ++it) {
    const int c = (wid * 6 + it) * 64 + lane;  // chunk 0..1535
    const int row = c / 24;                    // d (384B per row = 24 chunks)
    const int bir = (c % 24) * 16;
    const int swz = (bir & ~127) | ((bir ^ ((row & 7) << 4)) & 127);
    int sb = kstart + (swz >> 1);              // 8 s-values per chunk
    sb = sb < 0 ? 0 : (sb > S_LEN - 8 ? S_LEN - 8 : sb);   // clamp; P=0 masks garbage
    async16((char*)VT + (wid * 6 + it) * 1024, Vtb + (size_t)row * S_LEN + sb);
  }

  if (tid < 255) {                             // dist in [-127,127]
    const int di = tid - 127;
    const float fd = (float)di;
    tab[tid] = (di >= -64 && di <= 64)
        ? __expf(-fd * fd * 0.125f) + __cosf(0.06283185307179586f * fd)
        : -1e9f;
  }

  // Q fragments straight from global (A operand: row = lane&15)
  bf16x8 qf[2];
#pragma unroll
  for (int ks = 0; ks < 2; ++ks)
    qf[ks] = *reinterpret_cast<const bf16x8*>(Qb + (size_t)(q0 + wid * 16 + lc) * D_HEAD + ks * 32 + sub * 8);

  // QK^T: 12 col tiles of 16 keys, K fragments straight from global (clamped; masked later)
  f32x4 sc[12];
#pragma unroll
  for (int t = 0; t < 12; ++t) sc[t] = (f32x4){0.f, 0.f, 0.f, 0.f};
#pragma unroll
  for (int ks = 0; ks < 2; ++ks)
#pragma unroll
    for (int t = 0; t < 12; ++t) {
      int kg = kstart + t * 16 + lc;
      int kc = kg < 0 ? 0 : (kg > S_LEN - 1 ? S_LEN - 1 : kg);
      bf16x8 kf = *reinterpret_cast<const bf16x8*>(Kb + (size_t)kc * D_HEAD + ks * 32 + sub * 8);
      sc[t] = mfma16(qf[ks], kf, sc[t]);
    }
  __syncthreads();   // tab + VT ready (barrier drains vmcnt)

  // bias + mask + wave-parallel softmax (row lives across 16 lanes x 12 regs)
  float rmax[4] = {-3e38f, -3e38f, -3e38f, -3e38f};
#pragma unroll
  for (int t = 0; t < 12; ++t) {
    const int kk = t * 16 + lc;
    const int kg = kstart + kk;
    const bool valid = (kg >= 0) && (kg < S_LEN);
#pragma unroll
    for (int r = 0; r < 4; ++r) {
      const int qrow = wid * 16 + sub * 4 + r;
      const float bias = valid ? tab[qrow - kk + 191] : -1e9f;
      const float sv = sc[t][r] * 0.125f + bias;   // 1/sqrt(64)
      sc[t][r] = sv;
      rmax[r] = fmaxf(rmax[r], sv);
    }
  }
#pragma unroll
  for (int m = 1; m < 16; m <<= 1)
#pragma unroll
    for (int r = 0; r < 4; ++r) rmax[r] = fmaxf(rmax[r], __shfl_xor(rmax[r], m));
  float rsum[4] = {0.f, 0.f, 0.f, 0.f};
#pragma unroll
  for (int t = 0; t < 12; ++t)
#pragma unroll
    for (int r = 0; r < 4; ++r) {
      const float p = __expf(sc[t][r] - rmax[r]);
      sc[t][r] = p; rsum[r] += p;
    }
#pragma unroll
  for (int m = 1; m < 16; m <<= 1)
#pragma unroll
    for (int r = 0; r < 4; ++r) rsum[r] += __shfl_xor(rsum[r], m);
  float rinv[4];
#pragma unroll
  for (int r = 0; r < 4; ++r) rinv[r] = 1.0f / rsum[r];
#pragma unroll
  for (int t = 0; t < 12; ++t)
#pragma unroll
    for (int r = 0; r < 4; ++r) {
      const int qrow = wid * 16 + sub * 4 + r;
      *reinterpret_cast<u16*>(reinterpret_cast<char*>(P) + swz384(qrow, (t * 16 + lc) * 2))
          = f2bf(sc[t][r] * rinv[r]);
    }
  __syncthreads();   // P + VT consumable

  // PV: out[64q][64d], K-dim = 192 keys
  f32x4 oacc[4];
#pragma unroll
  for (int t = 0; t < 4; ++t) oacc[t] = (f32x4){0.f, 0.f, 0.f, 0.f};
  const int arow = wid * 16 + lc;
#pragma unroll
  for (int ks = 0; ks < 6; ++ks) {
    const int bir = ks * 64 + sub * 16;
    bf16x8 pa = *reinterpret_cast<const bf16x8*>(reinterpret_cast<char*>(P) + swz384(arow, bir));
#pragma unroll
    for (int t = 0; t < 4; ++t) {
      bf16x8 vb = *reinterpret_cast<const bf16x8*>(reinterpret_cast<char*>(VT) + swz384(t * 16 + lc, bir));
      oacc[t] = mfma16(pa, vb, oacc[t]);
    }
  }

  // write to [B,S,H*dh] bf16
  const size_t obase = ((size_t)bb * S_LEN + q0) * D_MOD + hh * D_HEAD;
#pragma unroll
  for (int t = 0; t < 4; ++t)
#pragma unroll
    for (int r = 0; r < 4; ++r) {
      const int qrow = wid * 16 + sub * 4 + r;
      Oflat[obase + (size_t)qrow * D_MOD + t * 16 + lc] = f2bf(oacc[t][r]);
    }
}

// ---------------- launch ----------------
extern "C" void kernel_launch(void* const* d_in, const int* in_sizes, int n_in,
                              void* d_out, int out_size, void* d_ws, size_t ws_size,
                              hipStream_t stream) {
  (void)in_sizes; (void)n_in; (void)out_size; (void)ws_size;
  const float* src  = (const float*)d_in[0];
  const float* Wq   = (const float*)d_in[1];
  const float* bq   = (const float*)d_in[2];
  const float* Wk   = (const float*)d_in[3];
  const float* bk   = (const float*)d_in[4];
  const float* Wv   = (const float*)d_in[5];
  const float* bv   = (const float*)d_in[6];
  const float* Wo   = (const float*)d_in[7];
  const float* bo   = (const float*)d_in[8];
  const float* Wg   = (const float*)d_in[9];
  const float* bg   = (const float*)d_in[10];
  const float* W1   = (const float*)d_in[11];
  const float* b1   = (const float*)d_in[12];
  const float* W2   = (const float*)d_in[13];
  const float* b2   = (const float*)d_in[14];
  const float* ln1g = (const float*)d_in[15];
  const float* ln1b = (const float*)d_in[16];
  const float* ln2g = (const float*)d_in[17];
  const float* ln2b = (const float*)d_in[18];
  float* out = (float*)d_out;

  char* ws = (char*)d_ws;
  u16*   WqkvT  = (u16*)  (ws + 0);            //  1,572,864
  u16*   WoT    = (u16*)  (ws + 1572864);      //    524,288
  u16*   W1T    = (u16*)  (ws + 2097152);      //  2,097,152
  u16*   W2T    = (u16*)  (ws + 4194304);      //  2,097,152
  float* gatef  = (float*)(ws + 6291456);      //     65,536
  u16*   Xbf    = (u16*)  (ws + 6356992);      // 16,777,216  [live until FF1 overwrites]
  u16*   QKVbf  = (u16*)  (ws + 23134208);     // 50,331,648  (Q,K planes; V plane unused)
  u16*   attnfl = (u16*)  (ws + 73465856);     // 16,777,216  [dead after proj]
  u16*   pr0    = (u16*)  (ws + 90243072);     // 16,777,216  (proj/ff2 partial z=0)
  u16*   pr1    = (u16*)  (ws + 107020288);    // 16,777,216  (proj/ff2 partial z=1)
  u16*   xbf2   = (u16*)  (ws + 123797504);    // 16,777,216  [live to end]
  u16*   VTg    = (u16*)  (ws + 140574720);    // 16,777,216  (V^T [bh][d][s]) -> 157,351,936 total
  u16*   hbuf   = Xbf;                         // FF1 out: 67,108,864 = Xbf+QKVbf regions
  u16*   pf0    = pr0;                         // FF2 partials reuse proj partials
  u16*   pf1    = pr1;

  // set once per call (idempotent; errors ignored — first, uncaptured, call sticks)
  (void)hipFuncSetAttribute((const void*)k_qkv,  hipFuncAttributeMaxDynamicSharedMemorySize, 131072);
  (void)hipFuncSetAttribute((const void*)k_ff1,  hipFuncAttributeMaxDynamicSharedMemorySize, 131072);
  (void)hipFuncSetAttribute((const void*)k_ff2,  hipFuncAttributeMaxDynamicSharedMemorySize, 131072);
  (void)hipFuncSetAttribute((const void*)k_proj, hipFuncAttributeMaxDynamicSharedMemorySize, 131072);

  dim3 tb(32, 8);
  cvt_gate<<<4096, 256, 0, stream>>>(src, Wg, bg, Xbf, gatef);
  transpose_cvt<<<dim3(16, 16), tb, 0, stream>>>(Wq, WqkvT,             512, 512);
  transpose_cvt<<<dim3(16, 16), tb, 0, stream>>>(Wk, WqkvT + 512 * 512, 512, 512);
  transpose_cvt<<<dim3(16, 16), tb, 0, stream>>>(Wv, WqkvT + 2 * 512 * 512, 512, 512);
  transpose_cvt<<<dim3(16, 16), tb, 0, stream>>>(Wo, WoT, 512, 512);
  transpose_cvt<<<dim3(64, 16), tb, 0, stream>>>(W1, W1T, 512, 2048);
  transpose_cvt<<<dim3(16, 64), tb, 0, stream>>>(W2, W2T, 2048, 512);

  EpiArgs e1{bq, bk, bv, nullptr, QKVbf, VTg};
  k_qkv<<<dim3(6, 64, 1), 512, 131072, stream>>>(Xbf, WqkvT, e1);

  attn_k<<<dim3(32, 64), 256, 0, stream>>>(QKVbf, QKVbf + BHSD, VTg, attnfl);

  EpiArgs e2{nullptr, nullptr, nullptr, nullptr, pr0, pr1};
  k_proj<<<dim3(2, 64, 2), 512, 131072, stream>>>(attnfl, WoT, e2);

  ln1red_k<<<4096, 256, 0, stream>>>(Xbf, gatef, pr0, pr1, bo, ln1g, ln1b, xbf2);

  EpiArgs e3{b1, nullptr, nullptr, nullptr, hbuf, nullptr};
  k_ff1<<<dim3(8, 64, 1), 512, 131072, stream>>>(xbf2, W1T, e3);

  EpiArgs e4{nullptr, nullptr, nullptr, nullptr, pf0, pf1};
  k_ff2<<<dim3(2, 64, 2), 512, 131072, stream>>>(hbuf, W2T, e4);

  ln2red_k<<<4096, 256, 0, stream>>>(xbf2, pf0, pf1, b2, ln2g, ln2b, out);
}

// Round 15
// 207.652 us; speedup vs baseline: 3.3416x; 1.0396x over previous
//
#include <hip/hip_runtime.h>
#include <hip/hip_bf16.h>
#include <math.h>

// Problem constants
#define S_LEN   2048
#define D_MOD   512
#define N_HEADS 8
#define D_HEAD  64
#define FF_DIM  2048
#define M_ROWS  16384            // B*S
#define BHSD    8388608          // 8*8*2048*64 elements per Q/K/V tensor

typedef __attribute__((ext_vector_type(8))) __bf16 bf16x8;
typedef __attribute__((ext_vector_type(4))) float  f32x4;
typedef unsigned short u16;

__device__ __forceinline__ u16 f2bf(float f) {           // RNE f32 -> bf16 bits
  unsigned u = __float_as_uint(f);
  u += 0x7fffu + ((u >> 16) & 1u);
  return (u16)(u >> 16);
}
__device__ __forceinline__ float bf2f(u16 h) { return __uint_as_float(((unsigned)h) << 16); }

__device__ __forceinline__ f32x4 mfma16(bf16x8 a, bf16x8 b, f32x4 c) {
  return __builtin_amdgcn_mfma_f32_16x16x32_bf16(a, b, c, 0, 0, 0);
}

// async global->LDS, 16B per lane; lds base wave-uniform (HW adds lane*16)
__device__ __forceinline__ void async16(void* lds, const void* g) {
  __builtin_amdgcn_global_load_lds(
      (const __attribute__((address_space(1))) unsigned int*)g,
      (__attribute__((address_space(3))) unsigned int*)lds, 16, 0, 0);
}

#define BAR()    asm volatile("s_barrier" ::: "memory")
#define WAITV(n) asm volatile("s_waitcnt vmcnt(" #n ")" ::: "memory")
#define WAITL()  asm volatile("s_waitcnt lgkmcnt(0)" ::: "memory")

// XOR swizzle within each 128B group of a 384B row (attn 64x192 bf16 tiles)
__device__ __forceinline__ int swz384(int row, int bir) {
  return row * 384 + ((bir & ~127) | ((bir ^ ((row & 7) << 4)) & 127));
}

// ---------------- fused prologue: 6 weight transposes + src->bf16 + gate ----------------
struct PreArgs {
  const float *Wq, *Wk, *Wv, *Wo, *W1, *W2;
  const float *src, *Wg, *bg;
  u16 *WqkvT, *WoT, *W1T, *W2T, *xb;
  float* gate;
};

__global__ __launch_bounds__(256) void prologue_k(PreArgs p) {
  const int bid = blockIdx.x;
  if (bid < 3072) {
    // ---- [K,N] f32 -> [N,K] bf16 transpose, 32x32 tile per block ----
    __shared__ float t[32][33];
    const int tid = threadIdx.x;
    const int tx = tid & 31, ty = tid >> 5;          // (32,8)
    const float* in; u16* out; int K, N, n0, k0;
    if (bid < 1024) {
      const int which = bid >> 8, tt = bid & 255;
      in  = (which == 0) ? p.Wq : (which == 1) ? p.Wk : (which == 2) ? p.Wv : p.Wo;
      out = (which == 3) ? p.WoT : (p.WqkvT + which * 262144);
      K = 512; N = 512;
      n0 = (tt & 15) * 32; k0 = (tt >> 4) * 32;
    } else if (bid < 2048) {
      const int tt = bid - 1024;
      in = p.W1; out = p.W1T; K = 512; N = 2048;
      n0 = (tt & 63) * 32; k0 = (tt >> 6) * 32;
    } else {
      const int tt = bid - 2048;
      in = p.W2; out = p.W2T; K = 2048; N = 512;
      n0 = (tt & 15) * 32; k0 = (tt >> 4) * 32;
    }
#pragma unroll
    for (int i = 0; i < 4; ++i)
      t[ty + 8 * i][tx] = in[(size_t)(k0 + ty + 8 * i) * N + n0 + tx];
    __syncthreads();
#pragma unroll
    for (int i = 0; i < 4; ++i)
      out[(size_t)(n0 + ty + 8 * i) * K + k0 + tx] = f2bf(t[tx][ty + 8 * i]);
  } else {
    // ---- src->bf16 + gate, one wave per row ----
    const int cb = bid - 3072;
    const int wid = threadIdx.x >> 6, lane = threadIdx.x & 63;
    const size_t row = (size_t)cb * 4 + wid;
    const float4* s = reinterpret_cast<const float4*>(p.src + row * D_MOD);
    const float4* w = reinterpret_cast<const float4*>(p.Wg);
    float4 a0 = s[lane * 2], a1 = s[lane * 2 + 1];
    float4 w0 = w[lane * 2], w1 = w[lane * 2 + 1];
    float acc = a0.x * w0.x + a0.y * w0.y + a0.z * w0.z + a0.w * w0.w +
                a1.x * w1.x + a1.y * w1.y + a1.z * w1.z + a1.w * w1.w;
#pragma unroll
    for (int m = 1; m < 64; m <<= 1) acc += __shfl_xor(acc, m);
    ushort4 h0, h1;
    h0.x = f2bf(a0.x); h0.y = f2bf(a0.y); h0.z = f2bf(a0.z); h0.w = f2bf(a0.w);
    h1.x = f2bf(a1.x); h1.y = f2bf(a1.y); h1.z = f2bf(a1.z); h1.w = f2bf(a1.w);
    ushort4* ob = reinterpret_cast<ushort4*>(p.xb + row * D_MOD);
    ob[lane * 2] = h0; ob[lane * 2 + 1] = h1;
    if (lane == 0) {
      float g = 1.f / (1.f + __expf(-(acc + p.bg[0])));
      p.gate[row] = g > 0.f ? g : 0.f;    // THRESH = 0
    }
  }
}

// ------ fused proj split-K reduce + bias + gate + residual(bf16) + layernorm 1 ------
__global__ __launch_bounds__(256) void ln1red_k(const u16* __restrict__ xb,
                                                const float* __restrict__ gate,
                                                const u16* __restrict__ p0,
                                                const u16* __restrict__ p1,
                                                const float* __restrict__ bo,
                                                const float* __restrict__ gam,
                                                const float* __restrict__ bet,
                                                u16* __restrict__ outb) {
  const int wid = threadIdx.x >> 6, lane = threadIdx.x & 63;
  const size_t row = (size_t)blockIdx.x * 4 + wid;
  const size_t base = row * D_MOD;
  const float g = gate[row];
  const ushort4* sp = reinterpret_cast<const ushort4*>(xb + base);
  const ushort4* a  = reinterpret_cast<const ushort4*>(p0 + base);
  const ushort4* c  = reinterpret_cast<const ushort4*>(p1 + base);
  const float4*  bb = reinterpret_cast<const float4*>(bo);
  ushort4 s0 = sp[lane * 2], s1 = sp[lane * 2 + 1];
  ushort4 a0 = a[lane * 2], a1 = a[lane * 2 + 1];
  ushort4 c0 = c[lane * 2], c1 = c[lane * 2 + 1];
  float4 d0 = bb[lane * 2], d1 = bb[lane * 2 + 1];
  float4 v0, v1;
  v0.x = bf2f(s0.x) + g * (bf2f(a0.x) + bf2f(c0.x) + d0.x);
  v0.y = bf2f(s0.y) + g * (bf2f(a0.y) + bf2f(c0.y) + d0.y);
  v0.z = bf2f(s0.z) + g * (bf2f(a0.z) + bf2f(c0.z) + d0.z);
  v0.w = bf2f(s0.w) + g * (bf2f(a0.w) + bf2f(c0.w) + d0.w);
  v1.x = bf2f(s1.x) + g * (bf2f(a1.x) + bf2f(c1.x) + d1.x);
  v1.y = bf2f(s1.y) + g * (bf2f(a1.y) + bf2f(c1.y) + d1.y);
  v1.z = bf2f(s1.z) + g * (bf2f(a1.z) + bf2f(c1.z) + d1.z);
  v1.w = bf2f(s1.w) + g * (bf2f(a1.w) + bf2f(c1.w) + d1.w);
  float s  = v0.x + v0.y + v0.z + v0.w + v1.x + v1.y + v1.z + v1.w;
  float s2 = v0.x * v0.x + v0.y * v0.y + v0.z * v0.z + v0.w * v0.w +
             v1.x * v1.x + v1.y * v1.y + v1.z * v1.z + v1.w * v1.w;
#pragma unroll
  for (int m = 1; m < 64; m <<= 1) { s += __shfl_xor(s, m); s2 += __shfl_xor(s2, m); }
  const float mu = s * (1.0f / 512.0f);
  const float var = s2 * (1.0f / 512.0f) - mu * mu;
  const float rs = 1.0f / sqrtf(var + 1e-5f);
  const float4* gp = reinterpret_cast<const float4*>(gam);
  const float4* bp = reinterpret_cast<const float4*>(bet);
  float4 g0 = gp[lane * 2], g1 = gp[lane * 2 + 1];
  float4 e0 = bp[lane * 2], e1 = bp[lane * 2 + 1];
  ushort4 h0, h1;
  h0.x = f2bf((v0.x - mu) * rs * g0.x + e0.x);  h0.y = f2bf((v0.y - mu) * rs * g0.y + e0.y);
  h0.z = f2bf((v0.z - mu) * rs * g0.z + e0.z);  h0.w = f2bf((v0.w - mu) * rs * g0.w + e0.w);
  h1.x = f2bf((v1.x - mu) * rs * g1.x + e1.x);  h1.y = f2bf((v1.y - mu) * rs * g1.y + e1.y);
  h1.z = f2bf((v1.z - mu) * rs * g1.z + e1.z);  h1.w = f2bf((v1.w - mu) * rs * g1.w + e1.w);
  ushort4* ob = reinterpret_cast<ushort4*>(outb + base);
  ob[lane * 2] = h0; ob[lane * 2 + 1] = h1;
}

// ---------------- fused FF2 split-K reduce + bias + residual + layernorm 2 ----------------
__global__ __launch_bounds__(256) void ln2red_k(const u16* __restrict__ xb,
                                                const u16* __restrict__ p0,
                                                const u16* __restrict__ p1,
                                                const float* __restrict__ b2,
                                                const float* __restrict__ gam,
                                                const float* __restrict__ bet,
                                                float* __restrict__ out) {
  const int wid = threadIdx.x >> 6, lane = threadIdx.x & 63;
  const size_t row = (size_t)blockIdx.x * 4 + wid;
  const size_t base = row * D_MOD;
  const ushort4* xp = reinterpret_cast<const ushort4*>(xb + base);
  const ushort4* q0 = reinterpret_cast<const ushort4*>(p0 + base);
  const ushort4* q1 = reinterpret_cast<const ushort4*>(p1 + base);
  const float4* bb = reinterpret_cast<const float4*>(b2);
  ushort4 h0 = xp[lane * 2], h1 = xp[lane * 2 + 1];
  ushort4 a0 = q0[lane * 2], a1 = q0[lane * 2 + 1];
  ushort4 c0 = q1[lane * 2], c1 = q1[lane * 2 + 1];
  float4 d0 = bb[lane * 2], d1 = bb[lane * 2 + 1];
  float4 v0, v1;
  v0.x = bf2f(h0.x) + bf2f(a0.x) + bf2f(c0.x) + d0.x;
  v0.y = bf2f(h0.y) + bf2f(a0.y) + bf2f(c0.y) + d0.y;
  v0.z = bf2f(h0.z) + bf2f(a0.z) + bf2f(c0.z) + d0.z;
  v0.w = bf2f(h0.w) + bf2f(a0.w) + bf2f(c0.w) + d0.w;
  v1.x = bf2f(h1.x) + bf2f(a1.x) + bf2f(c1.x) + d1.x;
  v1.y = bf2f(h1.y) + bf2f(a1.y) + bf2f(c1.y) + d1.y;
  v1.z = bf2f(h1.z) + bf2f(a1.z) + bf2f(c1.z) + d1.z;
  v1.w = bf2f(h1.w) + bf2f(a1.w) + bf2f(c1.w) + d1.w;
  float s  = v0.x + v0.y + v0.z + v0.w + v1.x + v1.y + v1.z + v1.w;
  float s2 = v0.x * v0.x + v0.y * v0.y + v0.z * v0.z + v0.w * v0.w +
             v1.x * v1.x + v1.y * v1.y + v1.z * v1.z + v1.w * v1.w;
#pragma unroll
  for (int m = 1; m < 64; m <<= 1) { s += __shfl_xor(s, m); s2 += __shfl_xor(s2, m); }
  const float mu = s * (1.0f / 512.0f);
  const float var = s2 * (1.0f / 512.0f) - mu * mu;
  const float rs = 1.0f / sqrtf(var + 1e-5f);
  const float4* gp = reinterpret_cast<const float4*>(gam);
  const float4* bp = reinterpret_cast<const float4*>(bet);
  float4 g0 = gp[lane * 2], g1 = gp[lane * 2 + 1];
  float4 e0 = bp[lane * 2], e1 = bp[lane * 2 + 1];
  float4 o0, o1;
  o0.x = (v0.x - mu) * rs * g0.x + e0.x;  o0.y = (v0.y - mu) * rs * g0.y + e0.y;
  o0.z = (v0.z - mu) * rs * g0.z + e0.z;  o0.w = (v0.w - mu) * rs * g0.w + e0.w;
  o1.x = (v1.x - mu) * rs * g1.x + e1.x;  o1.y = (v1.y - mu) * rs * g1.y + e1.y;
  o1.z = (v1.z - mu) * rs * g1.z + e1.z;  o1.w = (v1.w - mu) * rs * g1.w + e1.w;
  float4* q = reinterpret_cast<float4*>(out + base);
  q[lane * 2] = o0; q[lane * 2 + 1] = o1;
}

// ---------------- 256x256 deep-pipelined GEMM: C = A[M,K] @ Bt[N,K]^T ----------------
struct EpiArgs {
  const float* b0; const float* b1; const float* b2;   // biases
  float* outf; u16* outb; u16* outb2;
};

// EPI: 0 = QKV bias + Q/K scatter->bf16[2][B,H,S,dh] (outb) + V -> VT[bh][d][s] (outb2)
//      2 = relu(acc+b1)->bf16 [M,2048]   4 = raw bf16 partial (outb/outb2 by bz), stride 512
template<int EPI, int LD, int NT, int KSLICE, int GX, int GY>
__device__ __forceinline__ void gemm256_body(const u16* __restrict__ A,
                                             const u16* __restrict__ Bt, EpiArgs e) {
  extern __shared__ char smem[];
  char* Asb = smem;            // [2 buf][256 rows][128 B], row-swizzled via source
  char* Bsb = smem + 65536;
  const int tid = threadIdx.x;
  const int wid = tid >> 6, lane = tid & 63;
  const int sub = lane >> 4, lc = lane & 15;
  const int wr = wid >> 2, wcn = wid & 3;

  // flatten + bijective XCD swizzle (all grids are multiples of 8 blocks)
  const int nwg = (int)(gridDim.x * gridDim.y * gridDim.z);
  const int orig = ((int)blockIdx.z * (int)gridDim.y + (int)blockIdx.y) * (int)gridDim.x + (int)blockIdx.x;
  const int cpx = nwg >> 3;
  const int wg = (orig & 7) * cpx + (orig >> 3);
  const int bx = wg % GX;
  const int by = (wg / GX) % GY;
  const int bz = wg / (GX * GY);
  const int m0 = by * 256, n0 = bx * 256;
  const int kb = KSLICE * bz;

  const u16* Ab = A + (size_t)m0 * LD;
  const u16* Bb = Bt + (size_t)n0 * LD;

  f32x4 acc[8][4];
#pragma unroll
  for (int i = 0; i < 8; ++i)
#pragma unroll
    for (int j = 0; j < 4; ++j) acc[i][j] = (f32x4){0.f, 0.f, 0.f, 0.f};

  const int lr0 = tid >> 3;   // 0..63
  const int sl  = tid & 7;

  // stage one 256x64 bf16 tile (A or B): 4 x async16 per thread, source pre-swizzled
#define STAGE(BASE, SRC, BUF, KT)                                              \
  {                                                                            \
    const int kk_ = kb + (KT) * 64;                                            \
    _Pragma("unroll")                                                          \
    for (int r_ = 0; r_ < 4; ++r_) {                                           \
      const int lr_ = r_ * 64 + lr0;                                           \
      async16((BASE) + (BUF) * 32768 + r_ * 8192 + wid * 1024,                 \
              (SRC) + (size_t)lr_ * LD + kk_ + ((sl ^ (lr_ & 7)) << 3));       \
    }                                                                          \
  }
#define LDFRAG(BASE, ROW, KS) \
  (*reinterpret_cast<const bf16x8*>((BASE) + (ROW) * 128 + ((((KS) * 64) + sub * 16) ^ (((ROW) & 7) << 4))))

  // prologue: B0,A0,B1,A1 (issue order matters for vmcnt counting)
  STAGE(Bsb, Bb, 0, 0);
  STAGE(Asb, Ab, 0, 0);
  STAGE(Bsb, Bb, 1, 1);
  STAGE(Asb, Ab, 1, 1);
  WAITV(8);            // tile 0 landed, tile 1's 8 loads still in flight
  BAR();

  for (int t = 0; t < NT; ++t) {
    const int buf = t & 1;
    char* Abl = Asb + buf * 32768;
    char* Bbl = Bsb + buf * 32768;
    bf16x8 af[4][2], bfr[2][2][2];   // af: qr-half of A; bfr[qc][fc][ks]
    // ---- ph1: read A qr0 (8) + B qc0 (4); MFMA (qr0,qc0) ----
#pragma unroll
    for (int f = 0; f < 4; ++f) {
      const int row = wr * 128 + f * 16 + lc;
#pragma unroll
      for (int ks = 0; ks < 2; ++ks) af[f][ks] = LDFRAG(Abl, row, ks);
    }
#pragma unroll
    for (int f = 0; f < 2; ++f) {
      const int row = wcn * 64 + f * 16 + lc;
#pragma unroll
      for (int ks = 0; ks < 2; ++ks) bfr[0][f][ks] = LDFRAG(Bbl, row, ks);
    }
    __builtin_amdgcn_s_setprio(1);
#pragma unroll
    for (int f = 0; f < 4; ++f)
#pragma unroll
      for (int c = 0; c < 2; ++c)
#pragma unroll
        for (int ks = 0; ks < 2; ++ks)
          acc[f][c] = mfma16(af[f][ks], bfr[0][c][ks], acc[f][c]);
    __builtin_amdgcn_s_setprio(0);
    BAR();
    // ---- ph2: read B qc1 (4); MFMA (qr0,qc1) ----
#pragma unroll
    for (int f = 0; f < 2; ++f) {
      const int row = wcn * 64 + 32 + f * 16 + lc;
#pragma unroll
      for (int ks = 0; ks < 2; ++ks) bfr[1][f][ks] = LDFRAG(Bbl, row, ks);
    }
    __builtin_amdgcn_s_setprio(1);
#pragma unroll
    for (int f = 0; f < 4; ++f)
#pragma unroll
      for (int c = 0; c < 2; ++c)
#pragma unroll
        for (int ks = 0; ks < 2; ++ks)
          acc[f][2 + c] = mfma16(af[f][ks], bfr[1][c][ks], acc[f][2 + c]);
    __builtin_amdgcn_s_setprio(0);
    WAITL();           // all B (and A) LDS reads landed in regs before B region is re-staged
    BAR();
    // ---- ph3: stage B(t+2) into this buf; read A qr1 (8); MFMA (qr1,qc1) ----
    if (t + 2 < NT) STAGE(Bsb, Bb, buf, t + 2);
#pragma unroll
    for (int f = 0; f < 4; ++f) {
      const int row = wr * 128 + 64 + f * 16 + lc;
#pragma unroll
      for (int ks = 0; ks < 2; ++ks) af[f][ks] = LDFRAG(Abl, row, ks);
    }
    __builtin_amdgcn_s_setprio(1);
#pragma unroll
    for (int f = 0; f < 4; ++f)
#pragma unroll
      for (int c = 0; c < 2; ++c)
#pragma unroll
        for (int ks = 0; ks < 2; ++ks)
          acc[4 + f][2 + c] = mfma16(af[f][ks], bfr[1][c][ks], acc[4 + f][2 + c]);
    __builtin_amdgcn_s_setprio(0);
    WAITL();           // A qr1 reads landed before A region is re-staged
    BAR();
    // ---- ph4: stage A(t+2); MFMA (qr1,qc0); counted boundary wait ----
    if (t + 2 < NT) STAGE(Asb, Ab, buf, t + 2);
    __builtin_amdgcn_s_setprio(1);
#pragma unroll
    for (int f = 0; f < 4; ++f)
#pragma unroll
      for (int c = 0; c < 2; ++c)
#pragma unroll
        for (int ks = 0; ks < 2; ++ks)
          acc[4 + f][c] = mfma16(af[f][ks], bfr[0][c][ks], acc[4 + f][c]);
    __builtin_amdgcn_s_setprio(0);
    if (t + 1 < NT) {
      if (t + 2 < NT) { WAITV(8); } else { WAITV(0); }  // leave next-next tile in flight
      BAR();
    }
  }
#undef STAGE
#undef LDFRAG

  // ---- epilogue ----
  if constexpr (EPI == 2 || EPI == 4) {
    // direct semi-coalesced stores (32B per 16-lane group) — R7-proven best
#pragma unroll
    for (int fr = 0; fr < 8; ++fr) {
      const int row0 = m0 + wr * 128 + fr * 16 + sub * 4;
#pragma unroll
      for (int fc = 0; fc < 4; ++fc) {
        const int col = n0 + wcn * 64 + fc * 16 + lc;
        f32x4 v = acc[fr][fc];
#pragma unroll
        for (int i = 0; i < 4; ++i) {
          const int row = row0 + i;
          const float val = v[i];
          if constexpr (EPI == 2) {
            float o = val + e.b0[col];
            e.outb[(size_t)row * FF_DIM + col] = f2bf(o > 0.f ? o : 0.f);
          } else {
            u16* dst = (bz == 0) ? e.outb : e.outb2;
            dst[(size_t)row * D_MOD + col] = f2bf(val);
          }
        }
      }
    }
  } else {
    // EPI 0: which is block-uniform (n0>>9): 0=Q,1=K -> scatter; 2=V -> LDS transpose + coalesced
    const int which = n0 >> 9;
    const int bbi = m0 >> 11, ss0 = m0 & 2047;
    if (which == 2) {
      __syncthreads();
      u16* Cs = reinterpret_cast<u16*>(smem);   // Cs[nn][s]: 256 x 512B, swizzled
      const int nnb = n0 & 511;
#pragma unroll
      for (int fr = 0; fr < 8; ++fr) {
        const int lrow = wr * 128 + fr * 16 + sub * 4;   // local s
#pragma unroll
        for (int fc = 0; fc < 4; ++fc) {
          const int lcol = wcn * 64 + fc * 16 + lc;       // local nn
          const float bias = e.b2[nnb + lcol];
          f32x4 v = acc[fr][fc];
#pragma unroll
          for (int i = 0; i < 4; ++i) {
            const int row = lrow + i;
            const int sbyte = (row * 2) ^ ((lcol & 7) << 4);
            *reinterpret_cast<u16*>((char*)Cs + lcol * 512 + sbyte) = f2bf(v[i] + bias);
          }
        }
      }
      __syncthreads();
#pragma unroll
      for (int p = 0; p < 16; ++p) {
        const int off = p * 8192 + tid * 16;
        const int nn = off >> 9, cb = off & 511;          // nn = local col, cb = s-bytes
        const int cbs = cb ^ ((nn & 7) << 4);
        uint4 v = *reinterpret_cast<const uint4*>((const char*)Cs + nn * 512 + cbs);
        const int nng = nnb + nn;
        const int hh = nng >> 6, dd = nng & 63;
        *reinterpret_cast<uint4*>(
            (char*)(e.outb2 + (((size_t)bbi * N_HEADS + hh) * D_HEAD + dd) * S_LEN + ss0) + cb) = v;
      }
    } else {
#pragma unroll
      for (int fr = 0; fr < 8; ++fr) {
        const int row0 = m0 + wr * 128 + fr * 16 + sub * 4;
        const int ss = row0 & 2047;
#pragma unroll
        for (int fc = 0; fc < 4; ++fc) {
          const int col = n0 + wcn * 64 + fc * 16 + lc;
          const int nn = col & 511;
          const int hh = nn >> 6, dd = nn & 63;
          const float* bp = (which == 0) ? e.b0 : e.b1;
          const float bias = bp[nn];
          f32x4 v = acc[fr][fc];
#pragma unroll
          for (int i = 0; i < 4; ++i)
            e.outb[(size_t)which * BHSD +
                   (((size_t)bbi * N_HEADS + hh) * S_LEN + ss + i) * D_HEAD + dd]
                = f2bf(v[i] + bias);
        }
      }
    }
  }
}

__global__ __launch_bounds__(512, 2) void k_qkv(const u16* __restrict__ A, const u16* __restrict__ B, EpiArgs e) {
  gemm256_body<0, 512, 8, 0, 6, 64>(A, B, e);
}
__global__ __launch_bounds__(512, 2) void k_ff1(const u16* __restrict__ A, const u16* __restrict__ B, EpiArgs e) {
  gemm256_body<2, 512, 8, 0, 8, 64>(A, B, e);
}
__global__ __launch_bounds__(512, 2) void k_ff2(const u16* __restrict__ A, const u16* __restrict__ B, EpiArgs e) {
  gemm256_body<4, 2048, 16, 1024, 2, 64>(A, B, e);
}
__global__ __launch_bounds__(512, 2) void k_proj(const u16* __restrict__ A, const u16* __restrict__ B, EpiArgs e) {
  gemm256_body<4, 512, 4, 256, 2, 64>(A, B, e);
}

// ---------------- windowed attention: one block per (b,h, 64-query tile) ----------------
// R4-proven compute; V^T band staged via global_load_lds from pre-transposed VTg with
// inverse-swz384 source columns (LDS content identical to R4's VT).
__global__ __launch_bounds__(256)
void attn_k(const u16* __restrict__ Q, const u16* __restrict__ Kt,
            const u16* __restrict__ VTg, u16* __restrict__ Oflat) {
  __shared__ __align__(16) u16 VT[64 * 192];   // V^T (swz384): row=d, col=key
  __shared__ __align__(16) u16 P [64 * 192];   // probs (swz384): row=q, col=key
  __shared__ float tab[256];                   // bias table indexed by dist+127
  const int tid = threadIdx.x;
  const int wid = tid >> 6, lane = tid & 63;
  const int sub = lane >> 4, lc = lane & 15;
  const int qb = blockIdx.x, bh = blockIdx.y;
  const int bb = bh >> 3, hh = bh & 7;
  const int q0 = qb * 64, kstart = q0 - 64;    // 192-key band
  const u16* Qb = Q  + (size_t)bh * S_LEN * D_HEAD;
  const u16* Kb = Kt + (size_t)bh * S_LEN * D_HEAD;
  const u16* Vtb = VTg + (size_t)bh * D_HEAD * S_LEN;   // [d][s]

  // ---- V^T staging: 6 async16/thread, linear LDS dest, inverse-swz source cols ----
#pragma unroll
  for (int it = 0; it < 6; ++it) {
    const int c = (wid * 6 + it) * 64 + lane;  // chunk 0..1535
    const int row = c / 24;                    // d (384B per row = 24 chunks)
    const int bir = (c % 24) * 16;
    const int swz = (bir & ~127) | ((bir ^ ((row & 7) << 4)) & 127);
    int sb = kstart + (swz >> 1);              // 8 s-values per chunk
    sb = sb < 0 ? 0 : (sb > S_LEN - 8 ? S_LEN - 8 : sb);   // clamp; P=0 masks garbage
    async16((char*)VT + (wid * 6 + it) * 1024, Vtb + (size_t)row * S_LEN + sb);
  }

  if (tid < 255) {                             // dist in [-127,127]
    const int di = tid - 127;
    const float fd = (float)di;
    tab[tid] = (di >= -64 && di <= 64)
        ? __expf(-fd * fd * 0.125f) + __cosf(0.06283185307179586f * fd)
        : -1e9f;
  }

  // Q fragments straight from global (A operand: row = lane&15)
  bf16x8 qf[2];
#pragma unroll
  for (int ks = 0; ks < 2; ++ks)
    qf[ks] = *reinterpret_cast<const bf16x8*>(Qb + (size_t)(q0 + wid * 16 + lc) * D_HEAD + ks * 32 + sub * 8);

  // QK^T: 12 col tiles of 16 keys, K fragments straight from global (clamped; masked later)
  f32x4 sc[12];
#pragma unroll
  for (int t = 0; t < 12; ++t) sc[t] = (f32x4){0.f, 0.f, 0.f, 0.f};
#pragma unroll
  for (int ks = 0; ks < 2; ++ks)
#pragma unroll
    for (int t = 0; t < 12; ++t) {
      int kg = kstart + t * 16 + lc;
      int kc = kg < 0 ? 0 : (kg > S_LEN - 1 ? S_LEN - 1 : kg);
      bf16x8 kf = *reinterpret_cast<const bf16x8*>(Kb + (size_t)kc * D_HEAD + ks * 32 + sub * 8);
      sc[t] = mfma16(qf[ks], kf, sc[t]);
    }
  __syncthreads();   // tab + VT ready (barrier drains vmcnt)

  // bias + mask + wave-parallel softmax (row lives across 16 lanes x 12 regs)
  float rmax[4] = {-3e38f, -3e38f, -3e38f, -3e38f};
#pragma unroll
  for (int t = 0; t < 12; ++t) {
    const int kk = t * 16 + lc;
    const int kg = kstart + kk;
    const bool valid = (kg >= 0) && (kg < S_LEN);
#pragma unroll
    for (int r = 0; r < 4; ++r) {
      const int qrow = wid * 16 + sub * 4 + r;
      const float bias = valid ? tab[qrow - kk + 191] : -1e9f;
      const float sv = sc[t][r] * 0.125f + bias;   // 1/sqrt(64)
      sc[t][r] = sv;
      rmax[r] = fmaxf(rmax[r], sv);
    }
  }
#pragma unroll
  for (int m = 1; m < 16; m <<= 1)
#pragma unroll
    for (int r = 0; r < 4; ++r) rmax[r] = fmaxf(rmax[r], __shfl_xor(rmax[r], m));
  float rsum[4] = {0.f, 0.f, 0.f, 0.f};
#pragma unroll
  for (int t = 0; t < 12; ++t)
#pragma unroll
    for (int r = 0; r < 4; ++r) {
      const float p = __expf(sc[t][r] - rmax[r]);
      sc[t][r] = p; rsum[r] += p;
    }
#pragma unroll
  for (int m = 1; m < 16; m <<= 1)
#pragma unroll
    for (int r = 0; r < 4; ++r) rsum[r] += __shfl_xor(rsum[r], m);
  float rinv[4];
#pragma unroll
  for (int r = 0; r < 4; ++r) rinv[r] = 1.0f / rsum[r];
#pragma unroll
  for (int t = 0; t < 12; ++t)
#pragma unroll
    for (int r = 0; r < 4; ++r) {
      const int qrow = wid * 16 + sub * 4 + r;
      *reinterpret_cast<u16*>(reinterpret_cast<char*>(P) + swz384(qrow, (t * 16 + lc) * 2))
          = f2bf(sc[t][r] * rinv[r]);
    }
  __syncthreads();   // P + VT consumable

  // PV: out[64q][64d], K-dim = 192 keys
  f32x4 oacc[4];
#pragma unroll
  for (int t = 0; t < 4; ++t) oacc[t] = (f32x4){0.f, 0.f, 0.f, 0.f};
  const int arow = wid * 16 + lc;
#pragma unroll
  for (int ks = 0; ks < 6; ++ks) {
    const int bir = ks * 64 + sub * 16;
    bf16x8 pa = *reinterpret_cast<const bf16x8*>(reinterpret_cast<char*>(P) + swz384(arow, bir));
#pragma unroll
    for (int t = 0; t < 4; ++t) {
      bf16x8 vb = *reinterpret_cast<const bf16x8*>(reinterpret_cast<char*>(VT) + swz384(t * 16 + lc, bir));
      oacc[t] = mfma16(pa, vb, oacc[t]);
    }
  }

  // write to [B,S,H*dh] bf16
  const size_t obase = ((size_t)bb * S_LEN + q0) * D_MOD + hh * D_HEAD;
#pragma unroll
  for (int t = 0; t < 4; ++t)
#pragma unroll
    for (int r = 0; r < 4; ++r) {
      const int qrow = wid * 16 + sub * 4 + r;
      Oflat[obase + (size_t)qrow * D_MOD + t * 16 + lc] = f2bf(oacc[t][r]);
    }
}

// ---------------- launch ----------------
extern "C" void kernel_launch(void* const* d_in, const int* in_sizes, int n_in,
                              void* d_out, int out_size, void* d_ws, size_t ws_size,
                              hipStream_t stream) {
  (void)in_sizes; (void)n_in; (void)out_size; (void)ws_size;
  const float* src  = (const float*)d_in[0];
  const float* Wq   = (const float*)d_in[1];
  const float* bq   = (const float*)d_in[2];
  const float* Wk   = (const float*)d_in[3];
  const float* bk   = (const float*)d_in[4];
  const float* Wv   = (const float*)d_in[5];
  const float* bv   = (const float*)d_in[6];
  const float* Wo   = (const float*)d_in[7];
  const float* bo   = (const float*)d_in[8];
  const float* Wg   = (const float*)d_in[9];
  const float* bg   = (const float*)d_in[10];
  const float* W1   = (const float*)d_in[11];
  const float* b1   = (const float*)d_in[12];
  const float* W2   = (const float*)d_in[13];
  const float* b2   = (const float*)d_in[14];
  const float* ln1g = (const float*)d_in[15];
  const float* ln1b = (const float*)d_in[16];
  const float* ln2g = (const float*)d_in[17];
  const float* ln2b = (const float*)d_in[18];
  float* out = (float*)d_out;

  char* ws = (char*)d_ws;
  u16*   WqkvT  = (u16*)  (ws + 0);            //  1,572,864
  u16*   WoT    = (u16*)  (ws + 1572864);      //    524,288
  u16*   W1T    = (u16*)  (ws + 2097152);      //  2,097,152
  u16*   W2T    = (u16*)  (ws + 4194304);      //  2,097,152
  float* gatef  = (float*)(ws + 6291456);      //     65,536
  u16*   Xbf    = (u16*)  (ws + 6356992);      // 16,777,216  [live until FF1 overwrites]
  u16*   QKVbf  = (u16*)  (ws + 23134208);     // 50,331,648  (Q,K planes; V plane unused)
  u16*   attnfl = (u16*)  (ws + 73465856);     // 16,777,216  [dead after proj]
  u16*   pr0    = (u16*)  (ws + 90243072);     // 16,777,216  (proj/ff2 partial z=0)
  u16*   pr1    = (u16*)  (ws + 107020288);    // 16,777,216  (proj/ff2 partial z=1)
  u16*   xbf2   = (u16*)  (ws + 123797504);    // 16,777,216  [live to end]
  u16*   VTg    = (u16*)  (ws + 140574720);    // 16,777,216  (V^T [bh][d][s]) -> 157,351,936 total
  u16*   hbuf   = Xbf;                         // FF1 out: 67,108,864 = Xbf+QKVbf regions
  u16*   pf0    = pr0;                         // FF2 partials reuse proj partials
  u16*   pf1    = pr1;

  // set once per call (idempotent; errors ignored — first, uncaptured, call sticks)
  (void)hipFuncSetAttribute((const void*)k_qkv,  hipFuncAttributeMaxDynamicSharedMemorySize, 131072);
  (void)hipFuncSetAttribute((const void*)k_ff1,  hipFuncAttributeMaxDynamicSharedMemorySize, 131072);
  (void)hipFuncSetAttribute((const void*)k_ff2,  hipFuncAttributeMaxDynamicSharedMemorySize, 131072);
  (void)hipFuncSetAttribute((const void*)k_proj, hipFuncAttributeMaxDynamicSharedMemorySize, 131072);

  PreArgs pa{Wq, Wk, Wv, Wo, W1, W2, src, Wg, bg, WqkvT, WoT, W1T, W2T, Xbf, gatef};
  prologue_k<<<7168, 256, 0, stream>>>(pa);

  EpiArgs e1{bq, bk, bv, nullptr, QKVbf, VTg};
  k_qkv<<<dim3(6, 64, 1), 512, 131072, stream>>>(Xbf, WqkvT, e1);

  attn_k<<<dim3(32, 64), 256, 0, stream>>>(QKVbf, QKVbf + BHSD, VTg, attnfl);

  EpiArgs e2{nullptr, nullptr, nullptr, nullptr, pr0, pr1};
  k_proj<<<dim3(2, 64, 2), 512, 131072, stream>>>(attnfl, WoT, e2);

  ln1red_k<<<4096, 256, 0, stream>>>(Xbf, gatef, pr0, pr1, bo, ln1g, ln1b, xbf2);

  EpiArgs e3{b1, nullptr, nullptr, nullptr, hbuf, nullptr};
  k_ff1<<<dim3(8, 64, 1), 512, 131072, stream>>>(xbf2, W1T, e3);

  EpiArgs e4{nullptr, nullptr, nullptr, nullptr, pf0, pf1};
  k_ff2<<<dim3(2, 64, 2), 512, 131072, stream>>>(hbuf, W2T, e4);

  ln2red_k<<<4096, 256, 0, stream>>>(xbf2, pf0, pf1, b2, ln2g, ln2b, out);
}

// Round 16
// 205.938 us; speedup vs baseline: 3.3694x; 1.0083x over previous
//
#include <hip/hip_runtime.h>
#include <hip/hip_bf16.h>
#include <math.h>

// Problem constants
#define S_LEN   2048
#define D_MOD   512
#define N_HEADS 8
#define D_HEAD  64
#define FF_DIM  2048
#define M_ROWS  16384            // B*S
#define BHSD    8388608          // 8*8*2048*64 elements per Q/K/V tensor

typedef __attribute__((ext_vector_type(8))) __bf16 bf16x8;
typedef __attribute__((ext_vector_type(4))) float  f32x4;
typedef unsigned short u16;

__device__ __forceinline__ u16 f2bf(float f) {           // RNE f32 -> bf16 bits
  unsigned u = __float_as_uint(f);
  u += 0x7fffu + ((u >> 16) & 1u);
  return (u16)(u >> 16);
}
__device__ __forceinline__ float bf2f(u16 h) { return __uint_as_float(((unsigned)h) << 16); }

__device__ __forceinline__ f32x4 mfma16(bf16x8 a, bf16x8 b, f32x4 c) {
  return __builtin_amdgcn_mfma_f32_16x16x32_bf16(a, b, c, 0, 0, 0);
}

// async global->LDS, 16B per lane; lds base wave-uniform (HW adds lane*16)
__device__ __forceinline__ void async16(void* lds, const void* g) {
  __builtin_amdgcn_global_load_lds(
      (const __attribute__((address_space(1))) unsigned int*)g,
      (__attribute__((address_space(3))) unsigned int*)lds, 16, 0, 0);
}

#define BAR()    asm volatile("s_barrier" ::: "memory")
#define WAITV(n) asm volatile("s_waitcnt vmcnt(" #n ")" ::: "memory")
#define WAITL()  asm volatile("s_waitcnt lgkmcnt(0)" ::: "memory")

// XOR swizzle within each 128B group of a 384B row (attn 64x192 bf16 tiles)
__device__ __forceinline__ int swz384(int row, int bir) {
  return row * 384 + ((bir & ~127) | ((bir ^ ((row & 7) << 4)) & 127));
}

// ---------------- fused prologue: 6 weight transposes + src->bf16 + gate ----------------
struct PreArgs {
  const float *Wq, *Wk, *Wv, *Wo, *W1, *W2;
  const float *src, *Wg, *bg;
  u16 *WqkvT, *WoT, *W1T, *W2T, *xb;
  float* gate;
};

__global__ __launch_bounds__(256) void prologue_k(PreArgs p) {
  const int bid = blockIdx.x;
  if (bid < 3072) {
    // ---- [K,N] f32 -> [N,K] bf16 transpose, 32x32 tile per block ----
    __shared__ float t[32][33];
    const int tid = threadIdx.x;
    const int tx = tid & 31, ty = tid >> 5;          // (32,8)
    const float* in; u16* out; int K, N, n0, k0;
    if (bid < 1024) {
      const int which = bid >> 8, tt = bid & 255;
      in  = (which == 0) ? p.Wq : (which == 1) ? p.Wk : (which == 2) ? p.Wv : p.Wo;
      out = (which == 3) ? p.WoT : (p.WqkvT + which * 262144);
      K = 512; N = 512;
      n0 = (tt & 15) * 32; k0 = (tt >> 4) * 32;
    } else if (bid < 2048) {
      const int tt = bid - 1024;
      in = p.W1; out = p.W1T; K = 512; N = 2048;
      n0 = (tt & 63) * 32; k0 = (tt >> 6) * 32;
    } else {
      const int tt = bid - 2048;
      in = p.W2; out = p.W2T; K = 2048; N = 512;
      n0 = (tt & 15) * 32; k0 = (tt >> 4) * 32;
    }
#pragma unroll
    for (int i = 0; i < 4; ++i)
      t[ty + 8 * i][tx] = in[(size_t)(k0 + ty + 8 * i) * N + n0 + tx];
    __syncthreads();
#pragma unroll
    for (int i = 0; i < 4; ++i)
      out[(size_t)(n0 + ty + 8 * i) * K + k0 + tx] = f2bf(t[tx][ty + 8 * i]);
  } else {
    // ---- src->bf16 + gate, one wave per row ----
    const int cb = bid - 3072;
    const int wid = threadIdx.x >> 6, lane = threadIdx.x & 63;
    const size_t row = (size_t)cb * 4 + wid;
    const float4* s = reinterpret_cast<const float4*>(p.src + row * D_MOD);
    const float4* w = reinterpret_cast<const float4*>(p.Wg);
    float4 a0 = s[lane * 2], a1 = s[lane * 2 + 1];
    float4 w0 = w[lane * 2], w1 = w[lane * 2 + 1];
    float acc = a0.x * w0.x + a0.y * w0.y + a0.z * w0.z + a0.w * w0.w +
                a1.x * w1.x + a1.y * w1.y + a1.z * w1.z + a1.w * w1.w;
#pragma unroll
    for (int m = 1; m < 64; m <<= 1) acc += __shfl_xor(acc, m);
    ushort4 h0, h1;
    h0.x = f2bf(a0.x); h0.y = f2bf(a0.y); h0.z = f2bf(a0.z); h0.w = f2bf(a0.w);
    h1.x = f2bf(a1.x); h1.y = f2bf(a1.y); h1.z = f2bf(a1.z); h1.w = f2bf(a1.w);
    ushort4* ob = reinterpret_cast<ushort4*>(p.xb + row * D_MOD);
    ob[lane * 2] = h0; ob[lane * 2 + 1] = h1;
    if (lane == 0) {
      float g = 1.f / (1.f + __expf(-(acc + p.bg[0])));
      p.gate[row] = g > 0.f ? g : 0.f;    // THRESH = 0
    }
  }
}

// ------ fused proj split-K reduce + bias + gate + residual(bf16) + layernorm 1 ------
__global__ __launch_bounds__(256) void ln1red_k(const u16* __restrict__ xb,
                                                const float* __restrict__ gate,
                                                const u16* __restrict__ p0,
                                                const u16* __restrict__ p1,
                                                const float* __restrict__ bo,
                                                const float* __restrict__ gam,
                                                const float* __restrict__ bet,
                                                u16* __restrict__ outb) {
  const int wid = threadIdx.x >> 6, lane = threadIdx.x & 63;
  const size_t row = (size_t)blockIdx.x * 4 + wid;
  const size_t base = row * D_MOD;
  const float g = gate[row];
  const ushort4* sp = reinterpret_cast<const ushort4*>(xb + base);
  const ushort4* a  = reinterpret_cast<const ushort4*>(p0 + base);
  const ushort4* c  = reinterpret_cast<const ushort4*>(p1 + base);
  const float4*  bb = reinterpret_cast<const float4*>(bo);
  ushort4 s0 = sp[lane * 2], s1 = sp[lane * 2 + 1];
  ushort4 a0 = a[lane * 2], a1 = a[lane * 2 + 1];
  ushort4 c0 = c[lane * 2], c1 = c[lane * 2 + 1];
  float4 d0 = bb[lane * 2], d1 = bb[lane * 2 + 1];
  float4 v0, v1;
  v0.x = bf2f(s0.x) + g * (bf2f(a0.x) + bf2f(c0.x) + d0.x);
  v0.y = bf2f(s0.y) + g * (bf2f(a0.y) + bf2f(c0.y) + d0.y);
  v0.z = bf2f(s0.z) + g * (bf2f(a0.z) + bf2f(c0.z) + d0.z);
  v0.w = bf2f(s0.w) + g * (bf2f(a0.w) + bf2f(c0.w) + d0.w);
  v1.x = bf2f(s1.x) + g * (bf2f(a1.x) + bf2f(c1.x) + d1.x);
  v1.y = bf2f(s1.y) + g * (bf2f(a1.y) + bf2f(c1.y) + d1.y);
  v1.z = bf2f(s1.z) + g * (bf2f(a1.z) + bf2f(c1.z) + d1.z);
  v1.w = bf2f(s1.w) + g * (bf2f(a1.w) + bf2f(c1.w) + d1.w);
  float s  = v0.x + v0.y + v0.z + v0.w + v1.x + v1.y + v1.z + v1.w;
  float s2 = v0.x * v0.x + v0.y * v0.y + v0.z * v0.z + v0.w * v0.w +
             v1.x * v1.x + v1.y * v1.y + v1.z * v1.z + v1.w * v1.w;
#pragma unroll
  for (int m = 1; m < 64; m <<= 1) { s += __shfl_xor(s, m); s2 += __shfl_xor(s2, m); }
  const float mu = s * (1.0f / 512.0f);
  const float var = s2 * (1.0f / 512.0f) - mu * mu;
  const float rs = 1.0f / sqrtf(var + 1e-5f);
  const float4* gp = reinterpret_cast<const float4*>(gam);
  const float4* bp = reinterpret_cast<const float4*>(bet);
  float4 g0 = gp[lane * 2], g1 = gp[lane * 2 + 1];
  float4 e0 = bp[lane * 2], e1 = bp[lane * 2 + 1];
  ushort4 h0, h1;
  h0.x = f2bf((v0.x - mu) * rs * g0.x + e0.x);  h0.y = f2bf((v0.y - mu) * rs * g0.y + e0.y);
  h0.z = f2bf((v0.z - mu) * rs * g0.z + e0.z);  h0.w = f2bf((v0.w - mu) * rs * g0.w + e0.w);
  h1.x = f2bf((v1.x - mu) * rs * g1.x + e1.x);  h1.y = f2bf((v1.y - mu) * rs * g1.y + e1.y);
  h1.z = f2bf((v1.z - mu) * rs * g1.z + e1.z);  h1.w = f2bf((v1.w - mu) * rs * g1.w + e1.w);
  ushort4* ob = reinterpret_cast<ushort4*>(outb + base);
  ob[lane * 2] = h0; ob[lane * 2 + 1] = h1;
}

// ---------------- fused FF2 split-K reduce + bias + residual + layernorm 2 ----------------
__global__ __launch_bounds__(256) void ln2red_k(const u16* __restrict__ xb,
                                                const u16* __restrict__ p0,
                                                const u16* __restrict__ p1,
                                                const float* __restrict__ b2,
                                                const float* __restrict__ gam,
                                                const float* __restrict__ bet,
                                                float* __restrict__ out) {
  const int wid = threadIdx.x >> 6, lane = threadIdx.x & 63;
  const size_t row = (size_t)blockIdx.x * 4 + wid;
  const size_t base = row * D_MOD;
  const ushort4* xp = reinterpret_cast<const ushort4*>(xb + base);
  const ushort4* q0 = reinterpret_cast<const ushort4*>(p0 + base);
  const ushort4* q1 = reinterpret_cast<const ushort4*>(p1 + base);
  const float4* bb = reinterpret_cast<const float4*>(b2);
  ushort4 h0 = xp[lane * 2], h1 = xp[lane * 2 + 1];
  ushort4 a0 = q0[lane * 2], a1 = q0[lane * 2 + 1];
  ushort4 c0 = q1[lane * 2], c1 = q1[lane * 2 + 1];
  float4 d0 = bb[lane * 2], d1 = bb[lane * 2 + 1];
  float4 v0, v1;
  v0.x = bf2f(h0.x) + bf2f(a0.x) + bf2f(c0.x) + d0.x;
  v0.y = bf2f(h0.y) + bf2f(a0.y) + bf2f(c0.y) + d0.y;
  v0.z = bf2f(h0.z) + bf2f(a0.z) + bf2f(c0.z) + d0.z;
  v0.w = bf2f(h0.w) + bf2f(a0.w) + bf2f(c0.w) + d0.w;
  v1.x = bf2f(h1.x) + bf2f(a1.x) + bf2f(c1.x) + d1.x;
  v1.y = bf2f(h1.y) + bf2f(a1.y) + bf2f(c1.y) + d1.y;
  v1.z = bf2f(h1.z) + bf2f(a1.z) + bf2f(c1.z) + d1.z;
  v1.w = bf2f(h1.w) + bf2f(a1.w) + bf2f(c1.w) + d1.w;
  float s  = v0.x + v0.y + v0.z + v0.w + v1.x + v1.y + v1.z + v1.w;
  float s2 = v0.x * v0.x + v0.y * v0.y + v0.z * v0.z + v0.w * v0.w +
             v1.x * v1.x + v1.y * v1.y + v1.z * v1.z + v1.w * v1.w;
#pragma unroll
  for (int m = 1; m < 64; m <<= 1) { s += __shfl_xor(s, m); s2 += __shfl_xor(s2, m); }
  const float mu = s * (1.0f / 512.0f);
  const float var = s2 * (1.0f / 512.0f) - mu * mu;
  const float rs = 1.0f / sqrtf(var + 1e-5f);
  const float4* gp = reinterpret_cast<const float4*>(gam);
  const float4* bp = reinterpret_cast<const float4*>(bet);
  float4 g0 = gp[lane * 2], g1 = gp[lane * 2 + 1];
  float4 e0 = bp[lane * 2], e1 = bp[lane * 2 + 1];
  float4 o0, o1;
  o0.x = (v0.x - mu) * rs * g0.x + e0.x;  o0.y = (v0.y - mu) * rs * g0.y + e0.y;
  o0.z = (v0.z - mu) * rs * g0.z + e0.z;  o0.w = (v0.w - mu) * rs * g0.w + e0.w;
  o1.x = (v1.x - mu) * rs * g1.x + e1.x;  o1.y = (v1.y - mu) * rs * g1.y + e1.y;
  o1.z = (v1.z - mu) * rs * g1.z + e1.z;  o1.w = (v1.w - mu) * rs * g1.w + e1.w;
  float4* q = reinterpret_cast<float4*>(out + base);
  q[lane * 2] = o0; q[lane * 2 + 1] = o1;
}

// ---------------- 256x256 deep-pipelined GEMM: C = A[M,K] @ Bt[N,K]^T ----------------
struct EpiArgs {
  const float* b0; const float* b1; const float* b2;   // biases
  float* outf; u16* outb; u16* outb2;
};

// EPI: 0 = QKV bias + Q/K scatter->bf16[2][B,H,S,dh] (outb) + V -> VT[bh][d][s] (outb2)
//      2 = relu(acc+b1)->bf16 [M,2048]   4 = raw bf16 partial (outb/outb2 by bz), stride 512
template<int EPI, int LD, int NT, int KSLICE, int GX, int GY>
__device__ __forceinline__ void gemm256_body(const u16* __restrict__ A,
                                             const u16* __restrict__ Bt, EpiArgs e) {
  extern __shared__ char smem[];
  char* Asb = smem;            // [2 buf][256 rows][128 B], row-swizzled via source
  char* Bsb = smem + 65536;
  const int tid = threadIdx.x;
  const int wid = tid >> 6, lane = tid & 63;
  const int sub = lane >> 4, lc = lane & 15;
  const int wr = wid >> 2, wcn = wid & 3;

  // flatten + bijective XCD swizzle (all grids are multiples of 8 blocks)
  const int nwg = (int)(gridDim.x * gridDim.y * gridDim.z);
  const int orig = ((int)blockIdx.z * (int)gridDim.y + (int)blockIdx.y) * (int)gridDim.x + (int)blockIdx.x;
  const int cpx = nwg >> 3;
  const int wg = (orig & 7) * cpx + (orig >> 3);
  const int bx = wg % GX;
  const int by = (wg / GX) % GY;
  const int bz = wg / (GX * GY);
  const int m0 = by * 256, n0 = bx * 256;
  const int kb = KSLICE * bz;

  const u16* Ab = A + (size_t)m0 * LD;
  const u16* Bb = Bt + (size_t)n0 * LD;

  f32x4 acc[8][4];
#pragma unroll
  for (int i = 0; i < 8; ++i)
#pragma unroll
    for (int j = 0; j < 4; ++j) acc[i][j] = (f32x4){0.f, 0.f, 0.f, 0.f};

  const int lr0 = tid >> 3;   // 0..63
  const int sl  = tid & 7;

  // stage one 256x64 bf16 tile (A or B): 4 x async16 per thread, source pre-swizzled
#define STAGE(BASE, SRC, BUF, KT)                                              \
  {                                                                            \
    const int kk_ = kb + (KT) * 64;                                            \
    _Pragma("unroll")                                                          \
    for (int r_ = 0; r_ < 4; ++r_) {                                           \
      const int lr_ = r_ * 64 + lr0;                                           \
      async16((BASE) + (BUF) * 32768 + r_ * 8192 + wid * 1024,                 \
              (SRC) + (size_t)lr_ * LD + kk_ + ((sl ^ (lr_ & 7)) << 3));       \
    }                                                                          \
  }
#define LDFRAG(BASE, ROW, KS) \
  (*reinterpret_cast<const bf16x8*>((BASE) + (ROW) * 128 + ((((KS) * 64) + sub * 16) ^ (((ROW) & 7) << 4))))

  // prologue: B0,A0,B1,A1 (issue order matters for vmcnt counting)
  STAGE(Bsb, Bb, 0, 0);
  STAGE(Asb, Ab, 0, 0);
  STAGE(Bsb, Bb, 1, 1);
  STAGE(Asb, Ab, 1, 1);
  WAITV(8);            // tile 0 landed, tile 1's 8 loads still in flight
  BAR();

  for (int t = 0; t < NT; ++t) {
    const int buf = t & 1;
    char* Abl = Asb + buf * 32768;
    char* Bbl = Bsb + buf * 32768;
    bf16x8 af[4][2], bfr[2][2][2];   // af: qr-half of A; bfr[qc][fc][ks]
    // ---- ph1: read A qr0 (8) + B qc0 (4); MFMA (qr0,qc0) ----
#pragma unroll
    for (int f = 0; f < 4; ++f) {
      const int row = wr * 128 + f * 16 + lc;
#pragma unroll
      for (int ks = 0; ks < 2; ++ks) af[f][ks] = LDFRAG(Abl, row, ks);
    }
#pragma unroll
    for (int f = 0; f < 2; ++f) {
      const int row = wcn * 64 + f * 16 + lc;
#pragma unroll
      for (int ks = 0; ks < 2; ++ks) bfr[0][f][ks] = LDFRAG(Bbl, row, ks);
    }
    __builtin_amdgcn_s_setprio(1);
#pragma unroll
    for (int f = 0; f < 4; ++f)
#pragma unroll
      for (int c = 0; c < 2; ++c)
#pragma unroll
        for (int ks = 0; ks < 2; ++ks)
          acc[f][c] = mfma16(af[f][ks], bfr[0][c][ks], acc[f][c]);
    __builtin_amdgcn_s_setprio(0);
    BAR();
    // ---- ph2: read B qc1 (4); MFMA (qr0,qc1) ----
#pragma unroll
    for (int f = 0; f < 2; ++f) {
      const int row = wcn * 64 + 32 + f * 16 + lc;
#pragma unroll
      for (int ks = 0; ks < 2; ++ks) bfr[1][f][ks] = LDFRAG(Bbl, row, ks);
    }
    __builtin_amdgcn_s_setprio(1);
#pragma unroll
    for (int f = 0; f < 4; ++f)
#pragma unroll
      for (int c = 0; c < 2; ++c)
#pragma unroll
        for (int ks = 0; ks < 2; ++ks)
          acc[f][2 + c] = mfma16(af[f][ks], bfr[1][c][ks], acc[f][2 + c]);
    __builtin_amdgcn_s_setprio(0);
    WAITL();           // all B (and A) LDS reads landed in regs before B region is re-staged
    BAR();
    // ---- ph3: stage B(t+2) into this buf; read A qr1 (8); MFMA (qr1,qc1) ----
    if (t + 2 < NT) STAGE(Bsb, Bb, buf, t + 2);
#pragma unroll
    for (int f = 0; f < 4; ++f) {
      const int row = wr * 128 + 64 + f * 16 + lc;
#pragma unroll
      for (int ks = 0; ks < 2; ++ks) af[f][ks] = LDFRAG(Abl, row, ks);
    }
    __builtin_amdgcn_s_setprio(1);
#pragma unroll
    for (int f = 0; f < 4; ++f)
#pragma unroll
      for (int c = 0; c < 2; ++c)
#pragma unroll
        for (int ks = 0; ks < 2; ++ks)
          acc[4 + f][2 + c] = mfma16(af[f][ks], bfr[1][c][ks], acc[4 + f][2 + c]);
    __builtin_amdgcn_s_setprio(0);
    WAITL();           // A qr1 reads landed before A region is re-staged
    BAR();
    // ---- ph4: stage A(t+2); MFMA (qr1,qc0); counted boundary wait ----
    if (t + 2 < NT) STAGE(Asb, Ab, buf, t + 2);
    __builtin_amdgcn_s_setprio(1);
#pragma unroll
    for (int f = 0; f < 4; ++f)
#pragma unroll
      for (int c = 0; c < 2; ++c)
#pragma unroll
        for (int ks = 0; ks < 2; ++ks)
          acc[4 + f][c] = mfma16(af[f][ks], bfr[0][c][ks], acc[4 + f][c]);
    __builtin_amdgcn_s_setprio(0);
    if (t + 1 < NT) {
      if (t + 2 < NT) { WAITV(8); } else { WAITV(0); }  // leave next-next tile in flight
      BAR();
    }
  }
#undef STAGE
#undef LDFRAG

  // ---- epilogue ----
  if constexpr (EPI == 2 || EPI == 4) {
    // direct semi-coalesced stores (32B per 16-lane group) — R7-proven best
#pragma unroll
    for (int fr = 0; fr < 8; ++fr) {
      const int row0 = m0 + wr * 128 + fr * 16 + sub * 4;
#pragma unroll
      for (int fc = 0; fc < 4; ++fc) {
        const int col = n0 + wcn * 64 + fc * 16 + lc;
        f32x4 v = acc[fr][fc];
#pragma unroll
        for (int i = 0; i < 4; ++i) {
          const int row = row0 + i;
          const float val = v[i];
          if constexpr (EPI == 2) {
            float o = val + e.b0[col];
            e.outb[(size_t)row * FF_DIM + col] = f2bf(o > 0.f ? o : 0.f);
          } else {
            u16* dst = (bz == 0) ? e.outb : e.outb2;
            dst[(size_t)row * D_MOD + col] = f2bf(val);
          }
        }
      }
    }
  } else {
    // EPI 0: which is block-uniform (n0>>9): 0=Q,1=K -> scatter; 2=V -> LDS transpose + coalesced
    const int which = n0 >> 9;
    const int bbi = m0 >> 11, ss0 = m0 & 2047;
    if (which == 2) {
      __syncthreads();
      u16* Cs = reinterpret_cast<u16*>(smem);   // Cs[nn][s]: 256 x 512B, swizzled
      const int nnb = n0 & 511;
#pragma unroll
      for (int fr = 0; fr < 8; ++fr) {
        const int lrow = wr * 128 + fr * 16 + sub * 4;   // local s
#pragma unroll
        for (int fc = 0; fc < 4; ++fc) {
          const int lcol = wcn * 64 + fc * 16 + lc;       // local nn
          const float bias = e.b2[nnb + lcol];
          f32x4 v = acc[fr][fc];
#pragma unroll
          for (int i = 0; i < 4; ++i) {
            const int row = lrow + i;
            const int sbyte = (row * 2) ^ ((lcol & 7) << 4);
            *reinterpret_cast<u16*>((char*)Cs + lcol * 512 + sbyte) = f2bf(v[i] + bias);
          }
        }
      }
      __syncthreads();
#pragma unroll
      for (int p = 0; p < 16; ++p) {
        const int off = p * 8192 + tid * 16;
        const int nn = off >> 9, cb = off & 511;          // nn = local col, cb = s-bytes
        const int cbs = cb ^ ((nn & 7) << 4);
        uint4 v = *reinterpret_cast<const uint4*>((const char*)Cs + nn * 512 + cbs);
        const int nng = nnb + nn;
        const int hh = nng >> 6, dd = nng & 63;
        *reinterpret_cast<uint4*>(
            (char*)(e.outb2 + (((size_t)bbi * N_HEADS + hh) * D_HEAD + dd) * S_LEN + ss0) + cb) = v;
      }
    } else {
#pragma unroll
      for (int fr = 0; fr < 8; ++fr) {
        const int row0 = m0 + wr * 128 + fr * 16 + sub * 4;
        const int ss = row0 & 2047;
#pragma unroll
        for (int fc = 0; fc < 4; ++fc) {
          const int col = n0 + wcn * 64 + fc * 16 + lc;
          const int nn = col & 511;
          const int hh = nn >> 6, dd = nn & 63;
          const float* bp = (which == 0) ? e.b0 : e.b1;
          const float bias = bp[nn];
          f32x4 v = acc[fr][fc];
#pragma unroll
          for (int i = 0; i < 4; ++i)
            e.outb[(size_t)which * BHSD +
                   (((size_t)bbi * N_HEADS + hh) * S_LEN + ss + i) * D_HEAD + dd]
                = f2bf(v[i] + bias);
        }
      }
    }
  }
}

__global__ __launch_bounds__(512, 2) void k_qkv(const u16* __restrict__ A, const u16* __restrict__ B, EpiArgs e) {
  gemm256_body<0, 512, 8, 0, 6, 64>(A, B, e);
}
__global__ __launch_bounds__(512, 2) void k_ff1(const u16* __restrict__ A, const u16* __restrict__ B, EpiArgs e) {
  gemm256_body<2, 512, 8, 0, 8, 64>(A, B, e);
}
__global__ __launch_bounds__(512, 2) void k_ff2(const u16* __restrict__ A, const u16* __restrict__ B, EpiArgs e) {
  gemm256_body<4, 2048, 16, 1024, 2, 64>(A, B, e);
}
__global__ __launch_bounds__(512, 2) void k_proj(const u16* __restrict__ A, const u16* __restrict__ B, EpiArgs e) {
  gemm256_body<4, 512, 4, 256, 2, 64>(A, B, e);
}

// ---------------- windowed attention: one block per (b,h, 64-query tile) ----------------
// R4-proven compute; V^T band staged via global_load_lds from pre-transposed VTg.
// P rows are wave-private (write rows wid*16..wid*16+15, PV reads same range), so the
// second barrier is replaced by a per-wave WAITL. launch_bounds(256,3): 3 blocks/CU fit
// (LDS 3x49KB=147KB <= 160KB; VGPR cap 170 >= 76).
__global__ __launch_bounds__(256, 3)
void attn_k(const u16* __restrict__ Q, const u16* __restrict__ Kt,
            const u16* __restrict__ VTg, u16* __restrict__ Oflat) {
  __shared__ __align__(16) u16 VT[64 * 192];   // V^T (swz384): row=d, col=key
  __shared__ __align__(16) u16 P [64 * 192];   // probs (swz384): row=q, col=key
  __shared__ float tab[256];                   // bias table indexed by dist+127
  const int tid = threadIdx.x;
  const int wid = tid >> 6, lane = tid & 63;
  const int sub = lane >> 4, lc = lane & 15;
  const int qb = blockIdx.x, bh = blockIdx.y;
  const int bb = bh >> 3, hh = bh & 7;
  const int q0 = qb * 64, kstart = q0 - 64;    // 192-key band
  const u16* Qb = Q  + (size_t)bh * S_LEN * D_HEAD;
  const u16* Kb = Kt + (size_t)bh * S_LEN * D_HEAD;
  const u16* Vtb = VTg + (size_t)bh * D_HEAD * S_LEN;   // [d][s]

  // ---- V^T staging: 6 async16/thread, linear LDS dest, inverse-swz source cols ----
#pragma unroll
  for (int it = 0; it < 6; ++it) {
    const int c = (wid * 6 + it) * 64 + lane;  // chunk 0..1535
    const int row = c / 24;                    // d (384B per row = 24 chunks)
    const int bir = (c % 24) * 16;
    const int swz = (bir & ~127) | ((bir ^ ((row & 7) << 4)) & 127);
    int sb = kstart + (swz >> 1);              // 8 s-values per chunk
    sb = sb < 0 ? 0 : (sb > S_LEN - 8 ? S_LEN - 8 : sb);   // clamp; P=0 masks garbage
    async16((char*)VT + (wid * 6 + it) * 1024, Vtb + (size_t)row * S_LEN + sb);
  }

  if (tid < 255) {                             // dist in [-127,127]
    const int di = tid - 127;
    const float fd = (float)di;
    tab[tid] = (di >= -64 && di <= 64)
        ? __expf(-fd * fd * 0.125f) + __cosf(0.06283185307179586f * fd)
        : -1e9f;
  }

  // Q fragments straight from global (A operand: row = lane&15)
  bf16x8 qf[2];
#pragma unroll
  for (int ks = 0; ks < 2; ++ks)
    qf[ks] = *reinterpret_cast<const bf16x8*>(Qb + (size_t)(q0 + wid * 16 + lc) * D_HEAD + ks * 32 + sub * 8);

  // QK^T: 12 col tiles of 16 keys, K fragments straight from global (clamped; masked later)
  f32x4 sc[12];
#pragma unroll
  for (int t = 0; t < 12; ++t) sc[t] = (f32x4){0.f, 0.f, 0.f, 0.f};
#pragma unroll
  for (int ks = 0; ks < 2; ++ks)
#pragma unroll
    for (int t = 0; t < 12; ++t) {
      int kg = kstart + t * 16 + lc;
      int kc = kg < 0 ? 0 : (kg > S_LEN - 1 ? S_LEN - 1 : kg);
      bf16x8 kf = *reinterpret_cast<const bf16x8*>(Kb + (size_t)kc * D_HEAD + ks * 32 + sub * 8);
      sc[t] = mfma16(qf[ks], kf, sc[t]);
    }
  __syncthreads();   // tab + VT ready (barrier drains vmcnt)

  // bias + mask + wave-parallel softmax (row lives across 16 lanes x 12 regs)
  float rmax[4] = {-3e38f, -3e38f, -3e38f, -3e38f};
#pragma unroll
  for (int t = 0; t < 12; ++t) {
    const int kk = t * 16 + lc;
    const int kg = kstart + kk;
    const bool valid = (kg >= 0) && (kg < S_LEN);
#pragma unroll
    for (int r = 0; r < 4; ++r) {
      const int qrow = wid * 16 + sub * 4 + r;
      const float bias = valid ? tab[qrow - kk + 191] : -1e9f;
      const float sv = sc[t][r] * 0.125f + bias;   // 1/sqrt(64)
      sc[t][r] = sv;
      rmax[r] = fmaxf(rmax[r], sv);
    }
  }
#pragma unroll
  for (int m = 1; m < 16; m <<= 1)
#pragma unroll
    for (int r = 0; r < 4; ++r) rmax[r] = fmaxf(rmax[r], __shfl_xor(rmax[r], m));
  float rsum[4] = {0.f, 0.f, 0.f, 0.f};
#pragma unroll
  for (int t = 0; t < 12; ++t)
#pragma unroll
    for (int r = 0; r < 4; ++r) {
      const float p = __expf(sc[t][r] - rmax[r]);
      sc[t][r] = p; rsum[r] += p;
    }
#pragma unroll
  for (int m = 1; m < 16; m <<= 1)
#pragma unroll
    for (int r = 0; r < 4; ++r) rsum[r] += __shfl_xor(rsum[r], m);
  float rinv[4];
#pragma unroll
  for (int r = 0; r < 4; ++r) rinv[r] = 1.0f / rsum[r];
#pragma unroll
  for (int t = 0; t < 12; ++t)
#pragma unroll
    for (int r = 0; r < 4; ++r) {
      const int qrow = wid * 16 + sub * 4 + r;
      *reinterpret_cast<u16*>(reinterpret_cast<char*>(P) + swz384(qrow, (t * 16 + lc) * 2))
          = f2bf(sc[t][r] * rinv[r]);
    }
  WAITL();   // P rows are wave-private (rows wid*16..+15); DS in-order per wave suffices

  // PV: out[64q][64d], K-dim = 192 keys
  f32x4 oacc[4];
#pragma unroll
  for (int t = 0; t < 4; ++t) oacc[t] = (f32x4){0.f, 0.f, 0.f, 0.f};
  const int arow = wid * 16 + lc;
#pragma unroll
  for (int ks = 0; ks < 6; ++ks) {
    const int bir = ks * 64 + sub * 16;
    bf16x8 pa = *reinterpret_cast<const bf16x8*>(reinterpret_cast<char*>(P) + swz384(arow, bir));
#pragma unroll
    for (int t = 0; t < 4; ++t) {
      bf16x8 vb = *reinterpret_cast<const bf16x8*>(reinterpret_cast<char*>(VT) + swz384(t * 16 + lc, bir));
      oacc[t] = mfma16(pa, vb, oacc[t]);
    }
  }

  // write to [B,S,H*dh] bf16
  const size_t obase = ((size_t)bb * S_LEN + q0) * D_MOD + hh * D_HEAD;
#pragma unroll
  for (int t = 0; t < 4; ++t)
#pragma unroll
    for (int r = 0; r < 4; ++r) {
      const int qrow = wid * 16 + sub * 4 + r;
      Oflat[obase + (size_t)qrow * D_MOD + t * 16 + lc] = f2bf(oacc[t][r]);
    }
}

// ---------------- launch ----------------
extern "C" void kernel_launch(void* const* d_in, const int* in_sizes, int n_in,
                              void* d_out, int out_size, void* d_ws, size_t ws_size,
                              hipStream_t stream) {
  (void)in_sizes; (void)n_in; (void)out_size; (void)ws_size;
  const float* src  = (const float*)d_in[0];
  const float* Wq   = (const float*)d_in[1];
  const float* bq   = (const float*)d_in[2];
  const float* Wk   = (const float*)d_in[3];
  const float* bk   = (const float*)d_in[4];
  const float* Wv   = (const float*)d_in[5];
  const float* bv   = (const float*)d_in[6];
  const float* Wo   = (const float*)d_in[7];
  const float* bo   = (const float*)d_in[8];
  const float* Wg   = (const float*)d_in[9];
  const float* bg   = (const float*)d_in[10];
  const float* W1   = (const float*)d_in[11];
  const float* b1   = (const float*)d_in[12];
  const float* W2   = (const float*)d_in[13];
  const float* b2   = (const float*)d_in[14];
  const float* ln1g = (const float*)d_in[15];
  const float* ln1b = (const float*)d_in[16];
  const float* ln2g = (const float*)d_in[17];
  const float* ln2b = (const float*)d_in[18];
  float* out = (float*)d_out;

  char* ws = (char*)d_ws;
  u16*   WqkvT  = (u16*)  (ws + 0);            //  1,572,864
  u16*   WoT    = (u16*)  (ws + 1572864);      //    524,288
  u16*   W1T    = (u16*)  (ws + 2097152);      //  2,097,152
  u16*   W2T    = (u16*)  (ws + 4194304);      //  2,097,152
  float* gatef  = (float*)(ws + 6291456);      //     65,536
  u16*   Xbf    = (u16*)  (ws + 6356992);      // 16,777,216  [live until FF1 overwrites]
  u16*   QKVbf  = (u16*)  (ws + 23134208);     // 50,331,648  (Q,K planes; V plane unused)
  u16*   attnfl = (u16*)  (ws + 73465856);     // 16,777,216  [dead after proj]
  u16*   pr0    = (u16*)  (ws + 90243072);     // 16,777,216  (proj/ff2 partial z=0)
  u16*   pr1    = (u16*)  (ws + 107020288);    // 16,777,216  (proj/ff2 partial z=1)
  u16*   xbf2   = (u16*)  (ws + 123797504);    // 16,777,216  [live to end]
  u16*   VTg    = (u16*)  (ws + 140574720);    // 16,777,216  (V^T [bh][d][s]) -> 157,351,936 total
  u16*   hbuf   = Xbf;                         // FF1 out: 67,108,864 = Xbf+QKVbf regions
  u16*   pf0    = pr0;                         // FF2 partials reuse proj partials
  u16*   pf1    = pr1;

  // set once per call (idempotent; errors ignored — first, uncaptured, call sticks)
  (void)hipFuncSetAttribute((const void*)k_qkv,  hipFuncAttributeMaxDynamicSharedMemorySize, 131072);
  (void)hipFuncSetAttribute((const void*)k_ff1,  hipFuncAttributeMaxDynamicSharedMemorySize, 131072);
  (void)hipFuncSetAttribute((const void*)k_ff2,  hipFuncAttributeMaxDynamicSharedMemorySize, 131072);
  (void)hipFuncSetAttribute((const void*)k_proj, hipFuncAttributeMaxDynamicSharedMemorySize, 131072);

  PreArgs pa{Wq, Wk, Wv, Wo, W1, W2, src, Wg, bg, WqkvT, WoT, W1T, W2T, Xbf, gatef};
  prologue_k<<<7168, 256, 0, stream>>>(pa);

  EpiArgs e1{bq, bk, bv, nullptr, QKVbf, VTg};
  k_qkv<<<dim3(6, 64, 1), 512, 131072, stream>>>(Xbf, WqkvT, e1);

  attn_k<<<dim3(32, 64), 256, 0, stream>>>(QKVbf, QKVbf + BHSD, VTg, attnfl);

  EpiArgs e2{nullptr, nullptr, nullptr, nullptr, pr0, pr1};
  k_proj<<<dim3(2, 64, 2), 512, 131072, stream>>>(attnfl, WoT, e2);

  ln1red_k<<<4096, 256, 0, stream>>>(Xbf, gatef, pr0, pr1, bo, ln1g, ln1b, xbf2);

  EpiArgs e3{b1, nullptr, nullptr, nullptr, hbuf, nullptr};
  k_ff1<<<dim3(8, 64, 1), 512, 131072, stream>>>(xbf2, W1T, e3);

  EpiArgs e4{nullptr, nullptr, nullptr, nullptr, pf0, pf1};
  k_ff2<<<dim3(2, 64, 2), 512, 131072, stream>>>(hbuf, W2T, e4);

  ln2red_k<<<4096, 256, 0, stream>>>(xbf2, pf0, pf1, b2, ln2g, ln2b, out);
}